// Round 6
// baseline (160.123 us; speedup 1.0000x reference)
//
#include <hip/hip_runtime.h>
#include <cfloat>

#define SB 1024   // sequence length S = H*W
#define CC 512    // channels
#define NB 8      // batch
#define NH 8      // heads
#define HD 64     // head dim

typedef short short8 __attribute__((ext_vector_type(8)));
typedef short s16x4 __attribute__((ext_vector_type(4)));
typedef float f32x4 __attribute__((ext_vector_type(4)));

__device__ __forceinline__ short f2bs(float f) {
    union { float f; unsigned u; } x; x.f = f;
    unsigned r = x.u + 0x7fffu + ((x.u >> 16) & 1u);   // RNE to bf16
    return (short)(r >> 16);
}

__device__ __forceinline__ float bs2f(short s) {
    union { unsigned u; float f; } x;
    x.u = ((unsigned)(unsigned short)s) << 16;
    return x.f;
}

__device__ __forceinline__ void gload16(const void* g, void* l) {
    __builtin_amdgcn_global_load_lds(
        (const __attribute__((address_space(1))) unsigned int*)g,
        (__attribute__((address_space(3))) unsigned int*)l, 16, 0, 0);
}

// swizzled short-index within a [rows][64-short] LDS tile (128B rows)
__device__ __forceinline__ int sidx(int row, int colb) {
    return row * 64 + ((colb ^ ((row & 7) << 4)) >> 1);
}

// ---------------------------------------------------------------------------
// Convert both weight matrices fp32 -> bf16 (natural [o][c] layout).
// ---------------------------------------------------------------------------
__global__ __launch_bounds__(256)
void cvt_weights(const float* __restrict__ w1, const float* __restrict__ w2,
                 short* __restrict__ o1, short* __restrict__ o2)
{
    const int i4 = blockIdx.x * 256 + threadIdx.x;
    const int N1 = 1536 * 512 / 4;
    if (i4 < N1) {
        float4 v = *(const float4*)&w1[(size_t)i4 * 4];
        s16x4 p; p[0] = f2bs(v.x); p[1] = f2bs(v.y); p[2] = f2bs(v.z); p[3] = f2bs(v.w);
        *(s16x4*)&o1[(size_t)i4 * 4] = p;
    } else {
        const int j = i4 - N1;
        float4 v = *(const float4*)&w2[(size_t)j * 4];
        s16x4 p; p[0] = f2bs(v.x); p[1] = f2bs(v.y); p[2] = f2bs(v.z); p[3] = f2bs(v.w);
        *(s16x4*)&o2[(size_t)j * 4] = p;
    }
}

// ---------------------------------------------------------------------------
// x (B, C, S) fp32  ->  xT (B, S, C) bf16   (64x64 LDS tile transpose)
// ---------------------------------------------------------------------------
__global__ __launch_bounds__(256)
void transpose_x(const float* __restrict__ x, short* __restrict__ xT)
{
    const int bs = blockIdx.x, bc = blockIdx.y, b = blockIdx.z;
    const int tid = threadIdx.x;
    __shared__ short T[64][72];
    {
        const int cl = tid >> 4;
        const int s4 = (tid & 15) * 4;
        #pragma unroll
        for (int r = 0; r < 4; ++r) {
            const int c = cl + 16 * r;
            float4 v = *(const float4*)&x[((size_t)b * CC + bc * 64 + c) * SB + bs * 64 + s4];
            T[s4 + 0][c] = f2bs(v.x); T[s4 + 1][c] = f2bs(v.y);
            T[s4 + 2][c] = f2bs(v.z); T[s4 + 3][c] = f2bs(v.w);
        }
    }
    __syncthreads();
    {
        const int sl = tid >> 2;
        const int c16 = (tid & 3) * 16;
        short8 v0 = *(const short8*)&T[sl][c16];
        short8 v1 = *(const short8*)&T[sl][c16 + 8];
        short* dst = &xT[((size_t)b * SB + bs * 64 + sl) * CC + bc * 64 + c16];
        *(short8*)&dst[0] = v0;
        *(short8*)&dst[8] = v1;
    }
}

// ---------------------------------------------------------------------------
// vmean[b][c] = (1/S) sum_t v[b][c][t]; also expand mask -> float 0/-FLT_MAX.
// ---------------------------------------------------------------------------
__global__ __launch_bounds__(256)
void vmean_kernel(const short* __restrict__ vN, const int* __restrict__ mask,
                  float* __restrict__ vmean, float* __restrict__ maskf)
{
    const int gi = blockIdx.x * 256 + threadIdx.x;
    if (gi < NB * SB) maskf[gi] = (mask[gi] != 0) ? -FLT_MAX : 0.f;

    const int row = blockIdx.x * 4 + (threadIdx.x >> 6);  // b*CC + c
    const int lane = threadIdx.x & 63;
    const short* p = vN + (size_t)row * SB + lane * 16;
    short8 a = *(const short8*)&p[0];
    short8 b8 = *(const short8*)&p[8];
    float s = 0.f;
    #pragma unroll
    for (int j = 0; j < 8; ++j) s += bs2f(a[j]) + bs2f(b8[j]);
    #pragma unroll
    for (int o = 1; o < 64; o <<= 1) s += __shfl_xor(s, o, 64);
    if (lane == 0) vmean[row] = s * (1.f / 1024.f);
}

// ---------------------------------------------------------------------------
// bf16 MFMA GEMM: Y[b,o,s] = sum_c A[o,c] * X[b,s,c]^T + bias[o]
// 128x128 tile, BK=64, 4 waves (2x2), 4x4 16x16 frags per wave.
// MODE 0 (qkv): o<512 -> qT[b,h,s,d] *0.125; o<1024 -> kT[b,h,s,d]; else v[b,c,s].
// MODE 1 (proj): fp32 out[b,o,s].
// ---------------------------------------------------------------------------
template<int MODE>
__global__ __launch_bounds__(256)
void gemm_bf16(const short* __restrict__ A, const float* __restrict__ bias,
               const short* __restrict__ BT,
               short* __restrict__ qTo, short* __restrict__ kTo,
               short* __restrict__ vo, float* __restrict__ fo)
{
    const int stile = blockIdx.x * 128;
    const int bo    = blockIdx.y;
    const int b     = blockIdx.z;
    const int tid   = threadIdx.x;
    const int wave = tid >> 6, lane = tid & 63, lg = lane >> 4, ln = lane & 15;
    const int wm = wave >> 1, wn = wave & 1;

    __shared__ short Al[128 * 64];
    __shared__ short Bl[128 * 64];

    f32x4 acc[4][4];
    #pragma unroll
    for (int mt = 0; mt < 4; ++mt)
        #pragma unroll
        for (int nt = 0; nt < 4; ++nt) acc[mt][nt] = (f32x4){0.f, 0.f, 0.f, 0.f};

    const char* Ab = (const char*)(A + (size_t)bo * 128 * 512);
    const char* Bb = (const char*)(BT + ((size_t)b * SB + stile) * 512);

    for (int kc = 0; kc < 512; kc += 64) {
        __syncthreads();
        #pragma unroll
        for (int sw = 0; sw < 4; ++sw) {
            const int lin = tid * 16 + sw * 4096;
            const int row = lin >> 7;
            const int scol = (lin & 127) ^ ((row & 7) << 4);
            gload16(Ab + ((size_t)row * 512 + kc) * 2 + scol,
                    (char*)Al + (wave << 10) + (sw << 12));
            gload16(Bb + ((size_t)row * 512 + kc) * 2 + scol,
                    (char*)Bl + (wave << 10) + (sw << 12));
        }
        __syncthreads();
        #pragma unroll
        for (int kk = 0; kk < 2; ++kk) {
            const int colb = kk * 64 + lg * 16;
            short8 a[4], bb[4];
            #pragma unroll
            for (int mt = 0; mt < 4; ++mt)
                a[mt] = *(const short8*)&Al[sidx(wm * 64 + mt * 16 + ln, colb)];
            #pragma unroll
            for (int nt = 0; nt < 4; ++nt)
                bb[nt] = *(const short8*)&Bl[sidx(wn * 64 + nt * 16 + ln, colb)];
            #pragma unroll
            for (int mt = 0; mt < 4; ++mt)
                #pragma unroll
                for (int nt = 0; nt < 4; ++nt)
                    acc[mt][nt] = __builtin_amdgcn_mfma_f32_16x16x32_bf16(
                        a[mt], bb[nt], acc[mt][nt], 0, 0, 0);
        }
    }

    const int s_base = stile + wn * 64;
    if (MODE == 0) {
        if (bo < 8) {   // q or k -> transposed [b,h,s,d]
            short* dst = (bo < 4) ? qTo : kTo;
            const int h = (bo & 3) * 2 + wm;
            const float sc = (bo < 4) ? 0.125f : 1.0f;
            #pragma unroll
            for (int mt = 0; mt < 4; ++mt) {
                const int d0 = mt * 16 + 4 * lg;
                const int o0 = bo * 128 + wm * 64 + d0;
                const float b0 = bias[o0], b1 = bias[o0 + 1],
                            b2 = bias[o0 + 2], b3 = bias[o0 + 3];
                #pragma unroll
                for (int nt = 0; nt < 4; ++nt) {
                    const int s = s_base + nt * 16 + ln;
                    s16x4 pk;
                    pk[0] = f2bs((acc[mt][nt][0] + b0) * sc);
                    pk[1] = f2bs((acc[mt][nt][1] + b1) * sc);
                    pk[2] = f2bs((acc[mt][nt][2] + b2) * sc);
                    pk[3] = f2bs((acc[mt][nt][3] + b3) * sc);
                    *(s16x4*)&dst[(((size_t)b * NH + h) * SB + s) * HD + d0] = pk;
                }
            }
        } else {        // v -> natural [b,c,s]
            #pragma unroll
            for (int mt = 0; mt < 4; ++mt) {
                const int cv0 = (bo - 8) * 128 + wm * 64 + mt * 16 + 4 * lg;
                #pragma unroll
                for (int r = 0; r < 4; ++r) {
                    const float bv = bias[1024 + cv0 + r];
                    #pragma unroll
                    for (int nt = 0; nt < 4; ++nt) {
                        const int s = s_base + nt * 16 + ln;
                        vo[((size_t)b * CC + cv0 + r) * SB + s] = f2bs(acc[mt][nt][r] + bv);
                    }
                }
            }
        }
    } else {            // proj -> fp32 out [b,o,s]
        #pragma unroll
        for (int mt = 0; mt < 4; ++mt) {
            #pragma unroll
            for (int r = 0; r < 4; ++r) {
                const int o = bo * 128 + wm * 64 + mt * 16 + 4 * lg + r;
                const float bv = bias[o];
                #pragma unroll
                for (int nt = 0; nt < 4; ++nt) {
                    const int s = s_base + nt * 16 + ln;
                    fo[((size_t)b * CC + o) * SB + s] = acc[mt][nt][r] + bv;
                }
            }
        }
    }
}

// ---------------------------------------------------------------------------
// Split-key MFMA attention. Block = (bh, qb), 8 waves.
//  - Wave-group 0 (waves 0-3) handles key tiles [0,T0), group 1 [T0,qb+1),
//    T0 = ceil((qb+1)/2); partials (m,l,acc) merged through LDS at the end.
//    -> 1024 blocks x 8 waves = 8192 waves (4/SIMD resident at VGPR<=128).
//  - K/V fragments direct from global (L2-resident); K prefetched one tile
//    ahead in registers. No barriers inside the loop.
//  - Fully-masked rows (merged m == -FLT_MAX) get ctx = vmean, reproducing
//    the reference's uniform softmax over all 1024 keys. A group whose
//    partial is all-masked contributes exp(-FLT_MAX-finite)=0 on merge.
// ---------------------------------------------------------------------------
__global__ __launch_bounds__(512, 4)
void attn_mfma(const short* __restrict__ qT, const short* __restrict__ kT,
               const short* __restrict__ vN, const float* __restrict__ maskf,
               const float* __restrict__ vmean, short* __restrict__ ctxT)
{
    const int bh = blockIdx.x;            // 0..63 (same bh -> same XCD)
    const int b  = bh >> 3, h = bh & 7;
    const int qb = blockIdx.y;            // 0..15
    const int tid = threadIdx.x;
    const int wave = tid >> 6;            // 0..7
    const int grp  = wave >> 2;           // key-range half
    const int wsub = wave & 3;
    const int lane = tid & 63;
    const int lg = lane >> 4;
    const int ln = lane & 15;

    __shared__ float smem[6400];          // 25600B: Ps (18432B) / merge buffer
    short (*Ps)[16][72] = (short(*)[16][72])smem;

    const short* kbh = kT + (((size_t)b * NH + h) * SB) * HD;   // [s][d]
    const short* vbh = vN + ((size_t)b * CC + h * HD) * SB;     // [d][t]
    const float* mb  = maskf + (size_t)b * SB;

    const int T    = qb + 1;
    const int T0   = (T + 1) >> 1;
    const int tbeg = grp ? T0 : 0;
    const int tend = grp ? T : T0;

    const short* qrow = qT + (((size_t)b * NH + h) * SB + qb * 64 + wsub * 16 + ln) * HD;
    const short8 qa0 = *(const short8*)&qrow[8 * lg];
    const short8 qa1 = *(const short8*)&qrow[32 + 8 * lg];

    float m_[4], l_[4];
    f32x4 acc[4];
    #pragma unroll
    for (int r = 0; r < 4; ++r) { m_[r] = -FLT_MAX; l_[r] = 0.f; }
    #pragma unroll
    for (int nt = 0; nt < 4; ++nt) acc[nt] = (f32x4){0.f, 0.f, 0.f, 0.f};

    // preload K fragments for first tile of this group's range
    short8 kc0[4], kc1[4];
    #pragma unroll
    for (int nt = 0; nt < 4; ++nt) {
        const short* kr = kbh + (size_t)(tbeg * 64 + 16 * nt + ln) * HD;
        kc0[nt] = *(const short8*)&kr[8 * lg];
        kc1[nt] = *(const short8*)&kr[32 + 8 * lg];
    }

    for (int t = tbeg; t < tend; ++t) {
        const int tb = t * 64;

        float mf[4];
        #pragma unroll
        for (int nt = 0; nt < 4; ++nt) mf[nt] = mb[tb + 16 * nt + ln];

        // ---- QK^T from prefetched K fragments ----
        f32x4 sc[4];
        #pragma unroll
        for (int nt = 0; nt < 4; ++nt) {
            f32x4 z = (f32x4){0.f, 0.f, 0.f, 0.f};
            z = __builtin_amdgcn_mfma_f32_16x16x32_bf16(qa0, kc0[nt], z, 0, 0, 0);
            z = __builtin_amdgcn_mfma_f32_16x16x32_bf16(qa1, kc1[nt], z, 0, 0, 0);
            sc[nt] = z;
        }

        // ---- prefetch next tile's K (hidden under softmax) ----
        short8 kn0[4], kn1[4];
        if (t + 1 < tend) {
            #pragma unroll
            for (int nt = 0; nt < 4; ++nt) {
                const short* kr = kbh + (size_t)(tb + 64 + 16 * nt + ln) * HD;
                kn0[nt] = *(const short8*)&kr[8 * lg];
                kn1[nt] = *(const short8*)&kr[32 + 8 * lg];
            }
        }

        // ---- V fragments for this tile (issued early, consumed after SM) ----
        short8 vb0[4], vb1[4];
        #pragma unroll
        for (int nt = 0; nt < 4; ++nt) {
            const short* vr = vbh + (size_t)(16 * nt + ln) * SB + tb;
            vb0[nt] = *(const short8*)&vr[8 * lg];
            vb1[nt] = *(const short8*)&vr[32 + 8 * lg];
        }

        // ---- padding mask (float add) + causal on diagonal tile ----
        #pragma unroll
        for (int nt = 0; nt < 4; ++nt)
            #pragma unroll
            for (int r = 0; r < 4; ++r) sc[nt][r] += mf[nt];
        if (t == qb) {
            #pragma unroll
            for (int r = 0; r < 4; ++r) {
                const int so = wsub * 16 + 4 * lg + r;
                #pragma unroll
                for (int nt = 0; nt < 4; ++nt)
                    if (16 * nt + ln > so) sc[nt][r] = -FLT_MAX;
            }
        }

        // ---- online softmax ----
        #pragma unroll
        for (int r = 0; r < 4; ++r) {
            float mx = fmaxf(fmaxf(sc[0][r], sc[1][r]), fmaxf(sc[2][r], sc[3][r]));
            #pragma unroll
            for (int o = 1; o < 16; o <<= 1)
                mx = fmaxf(mx, __shfl_xor(mx, o, 64));
            const float mnew = fmaxf(m_[r], mx);
            const float f = __expf(m_[r] - mnew);   // 0-0 -> 1 (all-masked rows)
            float p[4], rs = 0.f;
            #pragma unroll
            for (int nt = 0; nt < 4; ++nt) {
                p[nt] = __expf(sc[nt][r] - mnew);
                rs += p[nt];
            }
            #pragma unroll
            for (int o = 1; o < 16; o <<= 1)
                rs += __shfl_xor(rs, o, 64);
            l_[r] = l_[r] * f + rs;
            m_[r] = mnew;
            #pragma unroll
            for (int nt = 0; nt < 4; ++nt) acc[nt][r] *= f;
            #pragma unroll
            for (int nt = 0; nt < 4; ++nt)
                Ps[wave][4 * lg + r][16 * nt + ln] = f2bs(p[nt]);
        }

        // ---- PV (Ps roundtrip within-wave; lgkmcnt orders it) ----
        const short8 pa0 = *(const short8*)&Ps[wave][ln][8 * lg];
        const short8 pa1 = *(const short8*)&Ps[wave][ln][32 + 8 * lg];
        #pragma unroll
        for (int nt = 0; nt < 4; ++nt) {
            acc[nt] = __builtin_amdgcn_mfma_f32_16x16x32_bf16(pa0, vb0[nt], acc[nt], 0, 0, 0);
            acc[nt] = __builtin_amdgcn_mfma_f32_16x16x32_bf16(pa1, vb1[nt], acc[nt], 0, 0, 0);
        }

        if (t + 1 < tend) {
            #pragma unroll
            for (int nt = 0; nt < 4; ++nt) { kc0[nt] = kn0[nt]; kc1[nt] = kn1[nt]; }
        }
    }

    // ---- merge group 1's partials into group 0 through LDS ----
    __syncthreads();
    float* my = smem + (wsub * 64 + lane) * 25;   // stride 25 -> conflict-free
    if (grp) {
        #pragma unroll
        for (int r = 0; r < 4; ++r) { my[r] = m_[r]; my[4 + r] = l_[r]; }
        #pragma unroll
        for (int nt = 0; nt < 4; ++nt)
            #pragma unroll
            for (int r = 0; r < 4; ++r) my[8 + 4 * nt + r] = acc[nt][r];
    }
    __syncthreads();
    if (!grp) {
        #pragma unroll
        for (int r = 0; r < 4; ++r) {
            const float mB = my[r], lB = my[4 + r];
            const float mn = fmaxf(m_[r], mB);
            const float fa = __expf(m_[r] - mn);
            const float fb = __expf(mB - mn);
            l_[r] = l_[r] * fa + lB * fb;
            m_[r] = mn;
            #pragma unroll
            for (int nt = 0; nt < 4; ++nt)
                acc[nt][r] = acc[nt][r] * fa + my[8 + 4 * nt + r] * fb;
        }

        // ---- epilogue: normalize (or vmean for fully-masked rows), store ----
        float rl[4];
        #pragma unroll
        for (int r = 0; r < 4; ++r) rl[r] = 1.f / l_[r];
        const float* vmb = vmean + (size_t)b * CC + h * HD;
        #pragma unroll
        for (int nt = 0; nt < 4; ++nt) {
            const int c = h * HD + 16 * nt + ln;
            const float vmv = vmb[16 * nt + ln];
            #pragma unroll
            for (int r = 0; r < 4; ++r) {
                const int s = qb * 64 + wsub * 16 + 4 * lg + r;
                const float val = (m_[r] == -FLT_MAX) ? vmv : acc[nt][r] * rl[r];
                ctxT[((size_t)b * SB + s) * CC + c] = f2bs(val);
            }
        }
    }
}

extern "C" void kernel_launch(void* const* d_in, const int* in_sizes, int n_in,
                              void* d_out, int out_size, void* d_ws, size_t ws_size,
                              hipStream_t stream) {
    const float* x      = (const float*)d_in[0];
    const int*   amask  = (const int*)d_in[1];
    const float* qkv_w  = (const float*)d_in[2];
    const float* qkv_b  = (const float*)d_in[3];
    const float* proj_w = (const float*)d_in[4];
    const float* proj_b = (const float*)d_in[5];
    float* out = (float*)d_out;

    short* xT    = (short*)d_ws;                       // (B,S,C)
    short* w1b   = xT  + (size_t)NB * SB * CC;         // (1536,512)
    short* w2b   = w1b + (size_t)1536 * 512;           // (512,512)
    short* qT    = w2b + (size_t)512 * 512;            // (B,H,S,D)
    short* kT    = qT  + (size_t)NB * NH * SB * HD;    // (B,H,S,D)
    short* vN    = kT  + (size_t)NB * NH * SB * HD;    // (B,C,S)
    short* ctxT  = vN  + (size_t)NB * CC * SB;         // (B,S,C)
    float* vmean = (float*)(ctxT + (size_t)NB * SB * CC);  // (B,C)
    float* maskf = vmean + (size_t)NB * CC;            // (B,S)

    cvt_weights<<<1024, 256, 0, stream>>>(qkv_w, proj_w, w1b, w2b);
    transpose_x<<<dim3(SB / 64, CC / 64, NB), 256, 0, stream>>>(x, xT);
    gemm_bf16<0><<<dim3(8, 12, NB), 256, 0, stream>>>(
        w1b, qkv_b, xT, qT, kT, vN, nullptr);
    vmean_kernel<<<NB * CC / 4, 256, 0, stream>>>(vN, amask, vmean, maskf);
    attn_mfma<<<dim3(NB * NH, 16, 1), 512, 0, stream>>>(qT, kT, vN, maskf, vmean, ctxT);
    gemm_bf16<1><<<dim3(8, 4, NB), 256, 0, stream>>>(
        w2b, proj_b, ctxT, nullptr, nullptr, nullptr, out);
}

// Round 7
// 135.414 us; speedup vs baseline: 1.1825x; 1.1825x over previous
//
#include <hip/hip_runtime.h>
#include <cfloat>

#define SB 1024   // sequence length S = H*W
#define CC 512    // channels
#define NB 8      // batch
#define NH 8      // heads
#define HD 64     // head dim

typedef short short8 __attribute__((ext_vector_type(8)));
typedef short s16x4 __attribute__((ext_vector_type(4)));
typedef float f32x4 __attribute__((ext_vector_type(4)));

__device__ __forceinline__ short f2bs(float f) {
    union { float f; unsigned u; } x; x.f = f;
    unsigned r = x.u + 0x7fffu + ((x.u >> 16) & 1u);   // RNE to bf16
    return (short)(r >> 16);
}

__device__ __forceinline__ float bs2f(short s) {
    union { unsigned u; float f; } x;
    x.u = ((unsigned)(unsigned short)s) << 16;
    return x.f;
}

__device__ __forceinline__ void gload16(const void* g, void* l) {
    __builtin_amdgcn_global_load_lds(
        (const __attribute__((address_space(1))) unsigned int*)g,
        (__attribute__((address_space(3))) unsigned int*)l, 16, 0, 0);
}

// swizzled short-index within a [rows][64-short] LDS tile (128B rows)
__device__ __forceinline__ int sidx(int row, int colb) {
    return row * 64 + ((colb ^ ((row & 7) << 4)) >> 1);
}

// ---------------------------------------------------------------------------
// Convert both weight matrices fp32 -> bf16 (natural [o][c] layout).
// ---------------------------------------------------------------------------
__global__ __launch_bounds__(256)
void cvt_weights(const float* __restrict__ w1, const float* __restrict__ w2,
                 short* __restrict__ o1, short* __restrict__ o2)
{
    const int i4 = blockIdx.x * 256 + threadIdx.x;
    const int N1 = 1536 * 512 / 4;
    if (i4 < N1) {
        float4 v = *(const float4*)&w1[(size_t)i4 * 4];
        s16x4 p; p[0] = f2bs(v.x); p[1] = f2bs(v.y); p[2] = f2bs(v.z); p[3] = f2bs(v.w);
        *(s16x4*)&o1[(size_t)i4 * 4] = p;
    } else {
        const int j = i4 - N1;
        float4 v = *(const float4*)&w2[(size_t)j * 4];
        s16x4 p; p[0] = f2bs(v.x); p[1] = f2bs(v.y); p[2] = f2bs(v.z); p[3] = f2bs(v.w);
        *(s16x4*)&o2[(size_t)j * 4] = p;
    }
}

// ---------------------------------------------------------------------------
// x (B, C, S) fp32  ->  xT (B, S, C) bf16   (64x64 LDS tile transpose)
// ---------------------------------------------------------------------------
__global__ __launch_bounds__(256)
void transpose_x(const float* __restrict__ x, short* __restrict__ xT)
{
    const int bs = blockIdx.x, bc = blockIdx.y, b = blockIdx.z;
    const int tid = threadIdx.x;
    __shared__ short T[64][72];
    {
        const int cl = tid >> 4;
        const int s4 = (tid & 15) * 4;
        #pragma unroll
        for (int r = 0; r < 4; ++r) {
            const int c = cl + 16 * r;
            float4 v = *(const float4*)&x[((size_t)b * CC + bc * 64 + c) * SB + bs * 64 + s4];
            T[s4 + 0][c] = f2bs(v.x); T[s4 + 1][c] = f2bs(v.y);
            T[s4 + 2][c] = f2bs(v.z); T[s4 + 3][c] = f2bs(v.w);
        }
    }
    __syncthreads();
    {
        const int sl = tid >> 2;
        const int c16 = (tid & 3) * 16;
        short8 v0 = *(const short8*)&T[sl][c16];
        short8 v1 = *(const short8*)&T[sl][c16 + 8];
        short* dst = &xT[((size_t)b * SB + bs * 64 + sl) * CC + bc * 64 + c16];
        *(short8*)&dst[0] = v0;
        *(short8*)&dst[8] = v1;
    }
}

// ---------------------------------------------------------------------------
// vmean[b][c] = (1/S) sum_t v[b][c][t]; also expand mask -> float 0/-FLT_MAX.
// ---------------------------------------------------------------------------
__global__ __launch_bounds__(256)
void vmean_kernel(const short* __restrict__ vN, const int* __restrict__ mask,
                  float* __restrict__ vmean, float* __restrict__ maskf)
{
    const int gi = blockIdx.x * 256 + threadIdx.x;
    if (gi < NB * SB) maskf[gi] = (mask[gi] != 0) ? -FLT_MAX : 0.f;

    const int row = blockIdx.x * 4 + (threadIdx.x >> 6);  // b*CC + c
    const int lane = threadIdx.x & 63;
    const short* p = vN + (size_t)row * SB + lane * 16;
    short8 a = *(const short8*)&p[0];
    short8 b8 = *(const short8*)&p[8];
    float s = 0.f;
    #pragma unroll
    for (int j = 0; j < 8; ++j) s += bs2f(a[j]) + bs2f(b8[j]);
    #pragma unroll
    for (int o = 1; o < 64; o <<= 1) s += __shfl_xor(s, o, 64);
    if (lane == 0) vmean[row] = s * (1.f / 1024.f);
}

// ---------------------------------------------------------------------------
// bf16 MFMA GEMM: Y[b,o,s] = sum_c A[o,c] * X[b,s,c]^T + bias[o]
// 128x128 tile, BK=64, 4 waves (2x2), 4x4 16x16 frags per wave.
// MODE 0 (qkv): o<512 -> qT[b,h,s,d] *0.125; o<1024 -> kT[b,h,s,d]; else v[b,c,s].
// MODE 1 (proj): fp32 out[b,o,s].
// ---------------------------------------------------------------------------
template<int MODE>
__global__ __launch_bounds__(256)
void gemm_bf16(const short* __restrict__ A, const float* __restrict__ bias,
               const short* __restrict__ BT,
               short* __restrict__ qTo, short* __restrict__ kTo,
               short* __restrict__ vo, float* __restrict__ fo)
{
    const int stile = blockIdx.x * 128;
    const int bo    = blockIdx.y;
    const int b     = blockIdx.z;
    const int tid   = threadIdx.x;
    const int wave = tid >> 6, lane = tid & 63, lg = lane >> 4, ln = lane & 15;
    const int wm = wave >> 1, wn = wave & 1;

    __shared__ short Al[128 * 64];
    __shared__ short Bl[128 * 64];

    f32x4 acc[4][4];
    #pragma unroll
    for (int mt = 0; mt < 4; ++mt)
        #pragma unroll
        for (int nt = 0; nt < 4; ++nt) acc[mt][nt] = (f32x4){0.f, 0.f, 0.f, 0.f};

    const char* Ab = (const char*)(A + (size_t)bo * 128 * 512);
    const char* Bb = (const char*)(BT + ((size_t)b * SB + stile) * 512);

    for (int kc = 0; kc < 512; kc += 64) {
        __syncthreads();
        #pragma unroll
        for (int sw = 0; sw < 4; ++sw) {
            const int lin = tid * 16 + sw * 4096;
            const int row = lin >> 7;
            const int scol = (lin & 127) ^ ((row & 7) << 4);
            gload16(Ab + ((size_t)row * 512 + kc) * 2 + scol,
                    (char*)Al + (wave << 10) + (sw << 12));
            gload16(Bb + ((size_t)row * 512 + kc) * 2 + scol,
                    (char*)Bl + (wave << 10) + (sw << 12));
        }
        __syncthreads();
        #pragma unroll
        for (int kk = 0; kk < 2; ++kk) {
            const int colb = kk * 64 + lg * 16;
            short8 a[4], bb[4];
            #pragma unroll
            for (int mt = 0; mt < 4; ++mt)
                a[mt] = *(const short8*)&Al[sidx(wm * 64 + mt * 16 + ln, colb)];
            #pragma unroll
            for (int nt = 0; nt < 4; ++nt)
                bb[nt] = *(const short8*)&Bl[sidx(wn * 64 + nt * 16 + ln, colb)];
            #pragma unroll
            for (int mt = 0; mt < 4; ++mt)
                #pragma unroll
                for (int nt = 0; nt < 4; ++nt)
                    acc[mt][nt] = __builtin_amdgcn_mfma_f32_16x16x32_bf16(
                        a[mt], bb[nt], acc[mt][nt], 0, 0, 0);
        }
    }

    const int s_base = stile + wn * 64;
    if (MODE == 0) {
        if (bo < 8) {   // q or k -> transposed [b,h,s,d]
            short* dst = (bo < 4) ? qTo : kTo;
            const int h = (bo & 3) * 2 + wm;
            const float sc = (bo < 4) ? 0.125f : 1.0f;
            #pragma unroll
            for (int mt = 0; mt < 4; ++mt) {
                const int d0 = mt * 16 + 4 * lg;
                const int o0 = bo * 128 + wm * 64 + d0;
                const float b0 = bias[o0], b1 = bias[o0 + 1],
                            b2 = bias[o0 + 2], b3 = bias[o0 + 3];
                #pragma unroll
                for (int nt = 0; nt < 4; ++nt) {
                    const int s = s_base + nt * 16 + ln;
                    s16x4 pk;
                    pk[0] = f2bs((acc[mt][nt][0] + b0) * sc);
                    pk[1] = f2bs((acc[mt][nt][1] + b1) * sc);
                    pk[2] = f2bs((acc[mt][nt][2] + b2) * sc);
                    pk[3] = f2bs((acc[mt][nt][3] + b3) * sc);
                    *(s16x4*)&dst[(((size_t)b * NH + h) * SB + s) * HD + d0] = pk;
                }
            }
        } else {        // v -> natural [b,c,s]
            #pragma unroll
            for (int mt = 0; mt < 4; ++mt) {
                const int cv0 = (bo - 8) * 128 + wm * 64 + mt * 16 + 4 * lg;
                #pragma unroll
                for (int r = 0; r < 4; ++r) {
                    const float bv = bias[1024 + cv0 + r];
                    #pragma unroll
                    for (int nt = 0; nt < 4; ++nt) {
                        const int s = s_base + nt * 16 + ln;
                        vo[((size_t)b * CC + cv0 + r) * SB + s] = f2bs(acc[mt][nt][r] + bv);
                    }
                }
            }
        }
    } else {            // proj -> fp32 out [b,o,s]
        #pragma unroll
        for (int mt = 0; mt < 4; ++mt) {
            #pragma unroll
            for (int r = 0; r < 4; ++r) {
                const int o = bo * 128 + wm * 64 + mt * 16 + 4 * lg + r;
                const float bv = bias[o];
                #pragma unroll
                for (int nt = 0; nt < 4; ++nt) {
                    const int s = s_base + nt * 16 + ln;
                    fo[((size_t)b * CC + o) * SB + s] = acc[mt][nt][r] + bv;
                }
            }
        }
    }
}

// ---------------------------------------------------------------------------
// Swapped-QK^T barrier-free MFMA attention. Block = 4 waves, one 64-q tile.
//  - QK^T computed as mfma(K,Q) = S^T: lane (lg,ln) owns 16 scores of query
//    ln -> softmax reduce = 15 in-reg fmax/add + 2 shfl_xor (was 32 shuffles).
//  - K/V fragments direct from global (L1/L2-resident, broadcast across the
//    4 waves); no LDS staging, no __syncthreads anywhere.
//  - XCD swizzle: bh = 8*(L&7) + ((L>>3)&7), qb = L>>6  ->  each XCD gets all
//    16 q-tiles of one batch (3 MB K/V/Q working set fits its 4 MB L2).
//  - Fully-masked rows (m stays exactly -FLT_MAX) get ctx = vmean,
//    reproducing the reference's uniform softmax over all 1024 keys.
// ---------------------------------------------------------------------------
__global__ __launch_bounds__(256)
void attn_mfma(const short* __restrict__ qT, const short* __restrict__ kT,
               const short* __restrict__ vN, const float* __restrict__ maskf,
               const float* __restrict__ vmean, short* __restrict__ ctxT)
{
    const int L  = blockIdx.x;
    const int bh = ((L & 7) << 3) | ((L >> 3) & 7);   // XCD co-location
    const int qb = L >> 6;                            // 0..15
    const int b  = bh >> 3, h = bh & 7;
    const int tid = threadIdx.x;
    const int wave = tid >> 6;
    const int lane = tid & 63;
    const int lg = lane >> 4;
    const int ln = lane & 15;

    __shared__ short Ps[4][16][72];       // per-wave P tile [s_local][t_local]

    const short* kbh = kT + (((size_t)b * NH + h) * SB) * HD;   // [s][d]
    const short* vbh = vN + ((size_t)b * CC + h * HD) * SB;     // [d][t]
    const float* mb  = maskf + (size_t)b * SB;

    // Q fragments: lane holds Q[s=base+ln][8lg+j] (B-frag content for S^T)
    const short* qrow = qT + (((size_t)b * NH + h) * SB + qb * 64 + wave * 16 + ln) * HD;
    const short8 qa0 = *(const short8*)&qrow[8 * lg];
    const short8 qa1 = *(const short8*)&qrow[32 + 8 * lg];

    float m_ = -FLT_MAX, l_ = 0.f;        // per-lane: state of query ln
    f32x4 acc[4];
    #pragma unroll
    for (int nt = 0; nt < 4; ++nt) acc[nt] = (f32x4){0.f, 0.f, 0.f, 0.f};

    for (int t = 0; t <= qb; ++t) {
        const int tb = t * 64;

        // ---- K A-frags: lane holds K[tb+16nt+ln][8lg+j] ----
        short8 ka0[4], ka1[4];
        #pragma unroll
        for (int nt = 0; nt < 4; ++nt) {
            const short* kr = kbh + (size_t)(tb + 16 * nt + ln) * HD;
            ka0[nt] = *(const short8*)&kr[8 * lg];
            ka1[nt] = *(const short8*)&kr[32 + 8 * lg];
        }

        // ---- swapped QK^T: sc[nt][r] = S[q=ln][key tb+16nt+4lg+r] ----
        f32x4 sc[4];
        #pragma unroll
        for (int nt = 0; nt < 4; ++nt) {
            f32x4 z = (f32x4){0.f, 0.f, 0.f, 0.f};
            z = __builtin_amdgcn_mfma_f32_16x16x32_bf16(ka0[nt], qa0, z, 0, 0, 0);
            z = __builtin_amdgcn_mfma_f32_16x16x32_bf16(ka1[nt], qa1, z, 0, 0, 0);
            sc[nt] = z;
        }

        // ---- V B-frags issued early (consumed after softmax) ----
        short8 vb0[4], vb1[4];
        #pragma unroll
        for (int nt = 0; nt < 4; ++nt) {
            const short* vr = vbh + (size_t)(16 * nt + ln) * SB + tb;
            vb0[nt] = *(const short8*)&vr[8 * lg];
            vb1[nt] = *(const short8*)&vr[32 + 8 * lg];
        }

        // ---- padding mask (float add; key index = tb+16nt+4lg+r) ----
        #pragma unroll
        for (int nt = 0; nt < 4; ++nt) {
            const float4 mf = *(const float4*)&mb[tb + 16 * nt + 4 * lg];
            sc[nt][0] += mf.x; sc[nt][1] += mf.y;
            sc[nt][2] += mf.z; sc[nt][3] += mf.w;
        }
        // ---- causal on diagonal tile ----
        if (t == qb) {
            const int so = wave * 16 + ln;
            #pragma unroll
            for (int nt = 0; nt < 4; ++nt)
                #pragma unroll
                for (int r = 0; r < 4; ++r)
                    if (16 * nt + 4 * lg + r > so) sc[nt][r] = -FLT_MAX;
        }

        // ---- softmax: owner-lane reduce (15 fmax + 2 shfl each way) ----
        float mx = sc[0][0];
        #pragma unroll
        for (int nt = 0; nt < 4; ++nt)
            #pragma unroll
            for (int r = 0; r < 4; ++r)
                if (nt || r) mx = fmaxf(mx, sc[nt][r]);
        mx = fmaxf(mx, __shfl_xor(mx, 16, 64));
        mx = fmaxf(mx, __shfl_xor(mx, 32, 64));
        const float mnew = fmaxf(m_, mx);
        const float fq = __expf(m_ - mnew);   // 0-0 -> 1 (all-masked rows)
        float rs = 0.f;
        #pragma unroll
        for (int nt = 0; nt < 4; ++nt)
            #pragma unroll
            for (int r = 0; r < 4; ++r) {
                const float p = __expf(sc[nt][r] - mnew);
                sc[nt][r] = p;
                rs += p;
            }
        rs += __shfl_xor(rs, 16, 64);
        rs += __shfl_xor(rs, 32, 64);
        l_ = l_ * fq + rs;
        m_ = mnew;

        // ---- P -> LDS [s][t] (row = own query ln) ----
        #pragma unroll
        for (int nt = 0; nt < 4; ++nt)
            #pragma unroll
            for (int r = 0; r < 4; ++r)
                Ps[wave][ln][16 * nt + 4 * lg + r] = f2bs(sc[nt][r]);

        // ---- rescale acc (acc row = query 4lg+r; fetch its f) ----
        float fr[4];
        #pragma unroll
        for (int r = 0; r < 4; ++r) fr[r] = __shfl(fq, 4 * lg + r, 64);
        #pragma unroll
        for (int nt = 0; nt < 4; ++nt)
            #pragma unroll
            for (int r = 0; r < 4; ++r) acc[nt][r] *= fr[r];

        // ---- PV (Ps roundtrip within-wave; lgkmcnt orders it) ----
        const short8 pa0 = *(const short8*)&Ps[wave][ln][8 * lg];
        const short8 pa1 = *(const short8*)&Ps[wave][ln][32 + 8 * lg];
        #pragma unroll
        for (int nt = 0; nt < 4; ++nt) {
            acc[nt] = __builtin_amdgcn_mfma_f32_16x16x32_bf16(pa0, vb0[nt], acc[nt], 0, 0, 0);
            acc[nt] = __builtin_amdgcn_mfma_f32_16x16x32_bf16(pa1, vb1[nt], acc[nt], 0, 0, 0);
        }
    }

    // ---- epilogue: fetch per-query l/m, normalize or vmean, store ----
    float rl[4], mch[4];
    #pragma unroll
    for (int r = 0; r < 4; ++r) {
        const float lq = __shfl(l_, 4 * lg + r, 64);
        mch[r] = __shfl(m_, 4 * lg + r, 64);
        rl[r] = 1.f / lq;
    }
    const float* vmb = vmean + (size_t)b * CC + h * HD;
    #pragma unroll
    for (int nt = 0; nt < 4; ++nt) {
        const int c = h * HD + 16 * nt + ln;
        const float vmv = vmb[16 * nt + ln];
        #pragma unroll
        for (int r = 0; r < 4; ++r) {
            const int s = qb * 64 + wave * 16 + 4 * lg + r;
            const float val = (mch[r] == -FLT_MAX) ? vmv : acc[nt][r] * rl[r];
            ctxT[((size_t)b * SB + s) * CC + c] = f2bs(val);
        }
    }
}

extern "C" void kernel_launch(void* const* d_in, const int* in_sizes, int n_in,
                              void* d_out, int out_size, void* d_ws, size_t ws_size,
                              hipStream_t stream) {
    const float* x      = (const float*)d_in[0];
    const int*   amask  = (const int*)d_in[1];
    const float* qkv_w  = (const float*)d_in[2];
    const float* qkv_b  = (const float*)d_in[3];
    const float* proj_w = (const float*)d_in[4];
    const float* proj_b = (const float*)d_in[5];
    float* out = (float*)d_out;

    short* xT    = (short*)d_ws;                       // (B,S,C)
    short* w1b   = xT  + (size_t)NB * SB * CC;         // (1536,512)
    short* w2b   = w1b + (size_t)1536 * 512;           // (512,512)
    short* qT    = w2b + (size_t)512 * 512;            // (B,H,S,D)
    short* kT    = qT  + (size_t)NB * NH * SB * HD;    // (B,H,S,D)
    short* vN    = kT  + (size_t)NB * NH * SB * HD;    // (B,C,S)
    short* ctxT  = vN  + (size_t)NB * CC * SB;         // (B,S,C)
    float* vmean = (float*)(ctxT + (size_t)NB * SB * CC);  // (B,C)
    float* maskf = vmean + (size_t)NB * CC;            // (B,S)

    cvt_weights<<<1024, 256, 0, stream>>>(qkv_w, proj_w, w1b, w2b);
    transpose_x<<<dim3(SB / 64, CC / 64, NB), 256, 0, stream>>>(x, xT);
    gemm_bf16<0><<<dim3(8, 12, NB), 256, 0, stream>>>(
        w1b, qkv_b, xT, qT, kT, vN, nullptr);
    vmean_kernel<<<NB * CC / 4, 256, 0, stream>>>(vN, amask, vmean, maskf);
    attn_mfma<<<dim3(1024, 1, 1), 256, 0, stream>>>(qT, kT, vN, maskf, vmean, ctxT);
    gemm_bf16<1><<<dim3(8, 4, NB), 256, 0, stream>>>(
        w2b, proj_b, ctxT, nullptr, nullptr, nullptr, out);
}

// Round 8
// 95.362 us; speedup vs baseline: 1.6791x; 1.4200x over previous
//
#include <hip/hip_runtime.h>
#include <cfloat>
#include <math.h>

#define SB 1024   // sequence length S = H*W
#define CC 512    // channels
#define NB 8      // batch
#define NH 8      // heads
#define HD 64     // head dim

typedef short short8 __attribute__((ext_vector_type(8)));
typedef short s16x4 __attribute__((ext_vector_type(4)));
typedef float f32x4 __attribute__((ext_vector_type(4)));

__device__ __forceinline__ short f2bs(float f) {
    union { float f; unsigned u; } x; x.f = f;
    unsigned r = x.u + 0x7fffu + ((x.u >> 16) & 1u);   // RNE to bf16
    return (short)(r >> 16);
}

__device__ __forceinline__ float bs2f(short s) {
    union { unsigned u; float f; } x;
    x.u = ((unsigned)(unsigned short)s) << 16;
    return x.f;
}

__device__ __forceinline__ void gload16(const void* g, void* l) {
    __builtin_amdgcn_global_load_lds(
        (const __attribute__((address_space(1))) unsigned int*)g,
        (__attribute__((address_space(3))) unsigned int*)l, 16, 0, 0);
}

// swizzled short-index within a [rows][64-short] LDS tile (128B rows)
__device__ __forceinline__ int sidx(int row, int colb) {
    return row * 64 + ((colb ^ ((row & 7) << 4)) >> 1);
}

// ---------------------------------------------------------------------------
// Convert both weight matrices fp32 -> bf16 (natural [o][c] layout).
// ---------------------------------------------------------------------------
__global__ __launch_bounds__(256)
void cvt_weights(const float* __restrict__ w1, const float* __restrict__ w2,
                 short* __restrict__ o1, short* __restrict__ o2)
{
    const int i4 = blockIdx.x * 256 + threadIdx.x;
    const int N1 = 1536 * 512 / 4;
    if (i4 < N1) {
        float4 v = *(const float4*)&w1[(size_t)i4 * 4];
        s16x4 p; p[0] = f2bs(v.x); p[1] = f2bs(v.y); p[2] = f2bs(v.z); p[3] = f2bs(v.w);
        *(s16x4*)&o1[(size_t)i4 * 4] = p;
    } else {
        const int j = i4 - N1;
        float4 v = *(const float4*)&w2[(size_t)j * 4];
        s16x4 p; p[0] = f2bs(v.x); p[1] = f2bs(v.y); p[2] = f2bs(v.z); p[3] = f2bs(v.w);
        *(s16x4*)&o2[(size_t)j * 4] = p;
    }
}

// ---------------------------------------------------------------------------
// x (B, C, S) fp32  ->  xT (B, S, C) bf16   (64x64 LDS tile transpose)
// ---------------------------------------------------------------------------
__global__ __launch_bounds__(256)
void transpose_x(const float* __restrict__ x, short* __restrict__ xT)
{
    const int bs = blockIdx.x, bc = blockIdx.y, b = blockIdx.z;
    const int tid = threadIdx.x;
    __shared__ short T[64][72];
    {
        const int cl = tid >> 4;
        const int s4 = (tid & 15) * 4;
        #pragma unroll
        for (int r = 0; r < 4; ++r) {
            const int c = cl + 16 * r;
            float4 v = *(const float4*)&x[((size_t)b * CC + bc * 64 + c) * SB + bs * 64 + s4];
            T[s4 + 0][c] = f2bs(v.x); T[s4 + 1][c] = f2bs(v.y);
            T[s4 + 2][c] = f2bs(v.z); T[s4 + 3][c] = f2bs(v.w);
        }
    }
    __syncthreads();
    {
        const int sl = tid >> 2;
        const int c16 = (tid & 3) * 16;
        short8 v0 = *(const short8*)&T[sl][c16];
        short8 v1 = *(const short8*)&T[sl][c16 + 8];
        short* dst = &xT[((size_t)b * SB + bs * 64 + sl) * CC + bc * 64 + c16];
        *(short8*)&dst[0] = v0;
        *(short8*)&dst[8] = v1;
    }
}

// ---------------------------------------------------------------------------
// vmean[b][c] = (1/S) sum_t v[b][c][t]; also expand mask -> float 0/-FLT_MAX.
// ---------------------------------------------------------------------------
__global__ __launch_bounds__(256)
void vmean_kernel(const short* __restrict__ vN, const int* __restrict__ mask,
                  float* __restrict__ vmean, float* __restrict__ maskf)
{
    const int gi = blockIdx.x * 256 + threadIdx.x;
    if (gi < NB * SB) maskf[gi] = (mask[gi] != 0) ? -FLT_MAX : 0.f;

    const int row = blockIdx.x * 4 + (threadIdx.x >> 6);  // b*CC + c
    const int lane = threadIdx.x & 63;
    const short* p = vN + (size_t)row * SB + lane * 16;
    short8 a = *(const short8*)&p[0];
    short8 b8 = *(const short8*)&p[8];
    float s = 0.f;
    #pragma unroll
    for (int j = 0; j < 8; ++j) s += bs2f(a[j]) + bs2f(b8[j]);
    #pragma unroll
    for (int o = 1; o < 64; o <<= 1) s += __shfl_xor(s, o, 64);
    if (lane == 0) vmean[row] = s * (1.f / 1024.f);
}

// ---------------------------------------------------------------------------
// bf16 MFMA GEMM: Y[b,o,s] = sum_c A[o,c] * X[b,s,c]^T + bias[o]
// 128x128 tile, BK=64, 4 waves (2x2), 4x4 16x16 frags per wave.
// MODE 0 (qkv): o<512 -> qT[b,h,s,d] * (0.125*log2e)  [exp2-domain scores];
//               o<1024 -> kT[b,h,s,d]; else v[b,c,s].
// MODE 1 (proj): fp32 out[b,o,s].
// ---------------------------------------------------------------------------
template<int MODE>
__global__ __launch_bounds__(256)
void gemm_bf16(const short* __restrict__ A, const float* __restrict__ bias,
               const short* __restrict__ BT,
               short* __restrict__ qTo, short* __restrict__ kTo,
               short* __restrict__ vo, float* __restrict__ fo)
{
    const int stile = blockIdx.x * 128;
    const int bo    = blockIdx.y;
    const int b     = blockIdx.z;
    const int tid   = threadIdx.x;
    const int wave = tid >> 6, lane = tid & 63, lg = lane >> 4, ln = lane & 15;
    const int wm = wave >> 1, wn = wave & 1;

    __shared__ short Al[128 * 64];
    __shared__ short Bl[128 * 64];

    f32x4 acc[4][4];
    #pragma unroll
    for (int mt = 0; mt < 4; ++mt)
        #pragma unroll
        for (int nt = 0; nt < 4; ++nt) acc[mt][nt] = (f32x4){0.f, 0.f, 0.f, 0.f};

    const char* Ab = (const char*)(A + (size_t)bo * 128 * 512);
    const char* Bb = (const char*)(BT + ((size_t)b * SB + stile) * 512);

    for (int kc = 0; kc < 512; kc += 64) {
        __syncthreads();
        #pragma unroll
        for (int sw = 0; sw < 4; ++sw) {
            const int lin = tid * 16 + sw * 4096;
            const int row = lin >> 7;
            const int scol = (lin & 127) ^ ((row & 7) << 4);
            gload16(Ab + ((size_t)row * 512 + kc) * 2 + scol,
                    (char*)Al + (wave << 10) + (sw << 12));
            gload16(Bb + ((size_t)row * 512 + kc) * 2 + scol,
                    (char*)Bl + (wave << 10) + (sw << 12));
        }
        __syncthreads();
        #pragma unroll
        for (int kk = 0; kk < 2; ++kk) {
            const int colb = kk * 64 + lg * 16;
            short8 a[4], bb[4];
            #pragma unroll
            for (int mt = 0; mt < 4; ++mt)
                a[mt] = *(const short8*)&Al[sidx(wm * 64 + mt * 16 + ln, colb)];
            #pragma unroll
            for (int nt = 0; nt < 4; ++nt)
                bb[nt] = *(const short8*)&Bl[sidx(wn * 64 + nt * 16 + ln, colb)];
            #pragma unroll
            for (int mt = 0; mt < 4; ++mt)
                #pragma unroll
                for (int nt = 0; nt < 4; ++nt)
                    acc[mt][nt] = __builtin_amdgcn_mfma_f32_16x16x32_bf16(
                        a[mt], bb[nt], acc[mt][nt], 0, 0, 0);
        }
    }

    const int s_base = stile + wn * 64;
    if (MODE == 0) {
        if (bo < 8) {   // q or k -> transposed [b,h,s,d]
            short* dst = (bo < 4) ? qTo : kTo;
            const int h = (bo & 3) * 2 + wm;
            const float sc = (bo < 4) ? 0.18033688011112042f : 1.0f;  // 0.125*log2(e)
            #pragma unroll
            for (int mt = 0; mt < 4; ++mt) {
                const int d0 = mt * 16 + 4 * lg;
                const int o0 = bo * 128 + wm * 64 + d0;
                const float b0 = bias[o0], b1 = bias[o0 + 1],
                            b2 = bias[o0 + 2], b3 = bias[o0 + 3];
                #pragma unroll
                for (int nt = 0; nt < 4; ++nt) {
                    const int s = s_base + nt * 16 + ln;
                    s16x4 pk;
                    pk[0] = f2bs((acc[mt][nt][0] + b0) * sc);
                    pk[1] = f2bs((acc[mt][nt][1] + b1) * sc);
                    pk[2] = f2bs((acc[mt][nt][2] + b2) * sc);
                    pk[3] = f2bs((acc[mt][nt][3] + b3) * sc);
                    *(s16x4*)&dst[(((size_t)b * NH + h) * SB + s) * HD + d0] = pk;
                }
            }
        } else {        // v -> natural [b,c,s]
            #pragma unroll
            for (int mt = 0; mt < 4; ++mt) {
                const int cv0 = (bo - 8) * 128 + wm * 64 + mt * 16 + 4 * lg;
                #pragma unroll
                for (int r = 0; r < 4; ++r) {
                    const float bv = bias[1024 + cv0 + r];
                    #pragma unroll
                    for (int nt = 0; nt < 4; ++nt) {
                        const int s = s_base + nt * 16 + ln;
                        vo[((size_t)b * CC + cv0 + r) * SB + s] = f2bs(acc[mt][nt][r] + bv);
                    }
                }
            }
        }
    } else {            // proj -> fp32 out [b,o,s]
        #pragma unroll
        for (int mt = 0; mt < 4; ++mt) {
            #pragma unroll
            for (int r = 0; r < 4; ++r) {
                const int o = bo * 128 + wm * 64 + mt * 16 + 4 * lg + r;
                const float bv = bias[o];
                #pragma unroll
                for (int nt = 0; nt < 4; ++nt) {
                    const int s = s_base + nt * 16 + ln;
                    fo[((size_t)b * CC + o) * SB + s] = acc[mt][nt][r] + bv;
                }
            }
        }
    }
}

// ---------------------------------------------------------------------------
// Double-buffered MFMA attention (R4 structure + 2-phase prefetch pipeline).
//  - K/V/mask staged to LDS via global_load_lds; tile t+1 issued BEFORE
//    compute of tile t; single __syncthreads per tile drains the prefetch
//    (T3 minimum-2-phase recipe) -> staging latency hidden under compute.
//  - Heavy-first linear grid: qb = 15-(L>>6) so long blocks dispatch first;
//    bh = L&63 puts all 16 q-blocks of one (b,h) on one XCD (L%8 == h).
//  - exp2-domain softmax (Q pre-scaled by 0.125*log2e in GEMM epilogue);
//    exp2f == bare v_exp_f32. Masked-row semantics preserved: fully-masked
//    rows keep m == -FLT_MAX, get ctx = vmean (uniform softmax) in epilogue.
//  - __launch_bounds__(256,4): VGPR cap 128 so the compiler does NOT
//    serialize fragment loads to hit a 64-VGPR allocation (R7 lesson).
// ---------------------------------------------------------------------------
__global__ __launch_bounds__(256, 4)
void attn_mfma(const short* __restrict__ qT, const short* __restrict__ kT,
               const short* __restrict__ vN, const float* __restrict__ maskf,
               const float* __restrict__ vmean, short* __restrict__ ctxT)
{
    const int L  = blockIdx.x;
    const int qb = 15 - (L >> 6);         // heavy blocks first
    const int bh = L & 63;                // XCD = L%8 = h -> per-(b,h) L2 reuse
    const int b  = bh >> 3, h = bh & 7;
    const int tid = threadIdx.x;
    const int wave = tid >> 6;
    const int lane = tid & 63;
    const int lg = lane >> 4;
    const int ln = lane & 15;

    __shared__ short Ks[2][64 * 64];      // [buf][t][d] swizzled
    __shared__ short Vs[2][64 * 64];      // [buf][d][t] swizzled
    __shared__ float mskL[2][64];         // 0 / -FLT_MAX per key
    __shared__ short Ps[4][16][72];       // per-wave P tile

    const char*  kbh = (const char*)(kT + (((size_t)b * NH + h) * SB) * HD);
    const char*  vbh = (const char*)(vN + ((size_t)b * CC + h * HD) * SB);
    const float* mb  = maskf + (size_t)b * SB;

    short8 qa0, qa1;
    {
        const short* qrow = qT + (((size_t)b * NH + h) * SB + qb * 64 + wave * 16 + ln) * HD;
        qa0 = *(const short8*)&qrow[8 * lg];
        qa1 = *(const short8*)&qrow[32 + 8 * lg];
    }

    float m_[4], l_[4];
    f32x4 acc[4];
    #pragma unroll
    for (int r = 0; r < 4; ++r) { m_[r] = -FLT_MAX; l_[r] = 0.f; }
    #pragma unroll
    for (int nt = 0; nt < 4; ++nt) acc[nt] = (f32x4){0.f, 0.f, 0.f, 0.f};

    // ---- staging helper (2 x 8KB via global_load_lds + 64 mask floats) ----
    auto stage = [&](int tb, int bi) {
        #pragma unroll
        for (int sw = 0; sw < 2; ++sw) {
            const int lin = tid * 16 + sw * 4096;
            const int row = lin >> 7;
            const int scol = (lin & 127) ^ ((row & 7) << 4);
            gload16(kbh + (size_t)tb * 128 + row * 128 + scol,
                    (char*)&Ks[bi][0] + (wave << 10) + (sw << 12));
            gload16(vbh + (size_t)row * (SB * 2) + tb * 2 + scol,
                    (char*)&Vs[bi][0] + (wave << 10) + (sw << 12));
        }
        if (tid < 64) mskL[bi][tid] = mb[tb + tid];
    };

    int cur = 0;
    stage(0, 0);
    __syncthreads();

    for (int t = 0; t <= qb; ++t) {
        // ---- issue next tile's staging BEFORE compute (overlap) ----
        if (t < qb) stage((t + 1) * 64, cur ^ 1);

        // ---- QK^T from LDS buf[cur] ----
        f32x4 sc[4];
        #pragma unroll
        for (int nt = 0; nt < 4; ++nt) {
            short8 kb0 = *(const short8*)&Ks[cur][sidx(ln + 16 * nt, lg * 16)];
            short8 kb1 = *(const short8*)&Ks[cur][sidx(ln + 16 * nt, 64 + lg * 16)];
            f32x4 z = (f32x4){0.f, 0.f, 0.f, 0.f};
            z = __builtin_amdgcn_mfma_f32_16x16x32_bf16(qa0, kb0, z, 0, 0, 0);
            z = __builtin_amdgcn_mfma_f32_16x16x32_bf16(qa1, kb1, z, 0, 0, 0);
            sc[nt] = z;
        }

        // ---- padding mask (float add) + causal on diagonal tile ----
        {
            float mf[4];
            #pragma unroll
            for (int nt = 0; nt < 4; ++nt) mf[nt] = mskL[cur][16 * nt + ln];
            #pragma unroll
            for (int nt = 0; nt < 4; ++nt)
                #pragma unroll
                for (int r = 0; r < 4; ++r) sc[nt][r] += mf[nt];
        }
        if (t == qb) {
            #pragma unroll
            for (int r = 0; r < 4; ++r) {
                const int so = wave * 16 + 4 * lg + r;
                #pragma unroll
                for (int nt = 0; nt < 4; ++nt)
                    if (16 * nt + ln > so) sc[nt][r] = -FLT_MAX;
            }
        }

        // ---- online softmax (exp2 domain; scores pre-scaled by log2e) ----
        #pragma unroll
        for (int r = 0; r < 4; ++r) {
            float mx = fmaxf(fmaxf(sc[0][r], sc[1][r]), fmaxf(sc[2][r], sc[3][r]));
            #pragma unroll
            for (int o = 1; o < 16; o <<= 1)
                mx = fmaxf(mx, __shfl_xor(mx, o, 64));
            const float mnew = fmaxf(m_[r], mx);
            const float f = exp2f(m_[r] - mnew);   // 0-0 -> 1 (all-masked rows)
            float p[4], rs = 0.f;
            #pragma unroll
            for (int nt = 0; nt < 4; ++nt) {
                p[nt] = exp2f(sc[nt][r] - mnew);
                rs += p[nt];
            }
            #pragma unroll
            for (int o = 1; o < 16; o <<= 1)
                rs += __shfl_xor(rs, o, 64);
            l_[r] = l_[r] * f + rs;
            m_[r] = mnew;
            #pragma unroll
            for (int nt = 0; nt < 4; ++nt) acc[nt][r] *= f;
            #pragma unroll
            for (int nt = 0; nt < 4; ++nt)
                Ps[wave][4 * lg + r][16 * nt + ln] = f2bs(p[nt]);
        }

        // ---- PV from LDS buf[cur] (Ps roundtrip within-wave) ----
        const short8 pa0 = *(const short8*)&Ps[wave][ln][8 * lg];
        const short8 pa1 = *(const short8*)&Ps[wave][ln][32 + 8 * lg];
        #pragma unroll
        for (int nt = 0; nt < 4; ++nt) {
            short8 vb0 = *(const short8*)&Vs[cur][sidx(16 * nt + ln, lg * 16)];
            short8 vb1 = *(const short8*)&Vs[cur][sidx(16 * nt + ln, 64 + lg * 16)];
            acc[nt] = __builtin_amdgcn_mfma_f32_16x16x32_bf16(pa0, vb0, acc[nt], 0, 0, 0);
            acc[nt] = __builtin_amdgcn_mfma_f32_16x16x32_bf16(pa1, vb1, acc[nt], 0, 0, 0);
        }

        // ---- publish buf[cur^1] (drains prefetch after compute) ----
        if (t < qb) {
            __syncthreads();
            cur ^= 1;
        }
    }

    // ---- epilogue: normalize (or vmean for fully-masked rows), store ----
    float rl[4];
    #pragma unroll
    for (int r = 0; r < 4; ++r) rl[r] = 1.f / l_[r];
    const float* vmb = vmean + (size_t)b * CC + h * HD;
    #pragma unroll
    for (int nt = 0; nt < 4; ++nt) {
        const int c = h * HD + 16 * nt + ln;
        const float vmv = vmb[16 * nt + ln];
        #pragma unroll
        for (int r = 0; r < 4; ++r) {
            const int s = qb * 64 + wave * 16 + 4 * lg + r;
            const float val = (m_[r] == -FLT_MAX) ? vmv : acc[nt][r] * rl[r];
            ctxT[((size_t)b * SB + s) * CC + c] = f2bs(val);
        }
    }
}

extern "C" void kernel_launch(void* const* d_in, const int* in_sizes, int n_in,
                              void* d_out, int out_size, void* d_ws, size_t ws_size,
                              hipStream_t stream) {
    const float* x      = (const float*)d_in[0];
    const int*   amask  = (const int*)d_in[1];
    const float* qkv_w  = (const float*)d_in[2];
    const float* qkv_b  = (const float*)d_in[3];
    const float* proj_w = (const float*)d_in[4];
    const float* proj_b = (const float*)d_in[5];
    float* out = (float*)d_out;

    short* xT    = (short*)d_ws;                       // (B,S,C)
    short* w1b   = xT  + (size_t)NB * SB * CC;         // (1536,512)
    short* w2b   = w1b + (size_t)1536 * 512;           // (512,512)
    short* qT    = w2b + (size_t)512 * 512;            // (B,H,S,D)
    short* kT    = qT  + (size_t)NB * NH * SB * HD;    // (B,H,S,D)
    short* vN    = kT  + (size_t)NB * NH * SB * HD;    // (B,C,S)
    short* ctxT  = vN  + (size_t)NB * CC * SB;         // (B,S,C)
    float* vmean = (float*)(ctxT + (size_t)NB * SB * CC);  // (B,C)
    float* maskf = vmean + (size_t)NB * CC;            // (B,S)

    cvt_weights<<<1024, 256, 0, stream>>>(qkv_w, proj_w, w1b, w2b);
    transpose_x<<<dim3(SB / 64, CC / 64, NB), 256, 0, stream>>>(x, xT);
    gemm_bf16<0><<<dim3(8, 12, NB), 256, 0, stream>>>(
        w1b, qkv_b, xT, qT, kT, vN, nullptr);
    vmean_kernel<<<NB * CC / 4, 256, 0, stream>>>(vN, amask, vmean, maskf);
    attn_mfma<<<dim3(1024, 1, 1), 256, 0, stream>>>(qT, kT, vN, maskf, vmean, ctxT);
    gemm_bf16<1><<<dim3(8, 4, NB), 256, 0, stream>>>(
        w2b, proj_b, ctxT, nullptr, nullptr, nullptr, out);
}

// Round 9
// 86.573 us; speedup vs baseline: 1.8496x; 1.1015x over previous
//
#include <hip/hip_runtime.h>
#include <cfloat>
#include <math.h>

#define SB 1024   // sequence length S = H*W
#define CC 512    // channels
#define NB 8      // batch
#define NH 8      // heads
#define HD 64     // head dim

typedef short short8 __attribute__((ext_vector_type(8)));
typedef short s16x4 __attribute__((ext_vector_type(4)));
typedef float f32x4 __attribute__((ext_vector_type(4)));

__device__ __forceinline__ short f2bs(float f) {
    union { float f; unsigned u; } x; x.f = f;
    unsigned r = x.u + 0x7fffu + ((x.u >> 16) & 1u);   // RNE to bf16
    return (short)(r >> 16);
}

__device__ __forceinline__ float bs2f(short s) {
    union { unsigned u; float f; } x;
    x.u = ((unsigned)(unsigned short)s) << 16;
    return x.f;
}

__device__ __forceinline__ void gload16(const void* g, void* l) {
    __builtin_amdgcn_global_load_lds(
        (const __attribute__((address_space(1))) unsigned int*)g,
        (__attribute__((address_space(3))) unsigned int*)l, 16, 0, 0);
}

// swizzled short-index within a [rows][64-short] LDS tile (128B rows)
__device__ __forceinline__ int sidx(int row, int colb) {
    return row * 64 + ((colb ^ ((row & 7) << 4)) >> 1);
}

// ---------------------------------------------------------------------------
// Convert both weight matrices fp32 -> bf16 (natural [o][c] layout).
// ---------------------------------------------------------------------------
__global__ __launch_bounds__(256)
void cvt_weights(const float* __restrict__ w1, const float* __restrict__ w2,
                 short* __restrict__ o1, short* __restrict__ o2)
{
    const int i4 = blockIdx.x * 256 + threadIdx.x;
    const int N1 = 1536 * 512 / 4;
    if (i4 < N1) {
        float4 v = *(const float4*)&w1[(size_t)i4 * 4];
        s16x4 p; p[0] = f2bs(v.x); p[1] = f2bs(v.y); p[2] = f2bs(v.z); p[3] = f2bs(v.w);
        *(s16x4*)&o1[(size_t)i4 * 4] = p;
    } else {
        const int j = i4 - N1;
        float4 v = *(const float4*)&w2[(size_t)j * 4];
        s16x4 p; p[0] = f2bs(v.x); p[1] = f2bs(v.y); p[2] = f2bs(v.z); p[3] = f2bs(v.w);
        *(s16x4*)&o2[(size_t)j * 4] = p;
    }
}

// ---------------------------------------------------------------------------
// x (B, C, S) fp32  ->  xT (B, S, C) bf16   (64x64 LDS tile transpose)
// ---------------------------------------------------------------------------
__global__ __launch_bounds__(256)
void transpose_x(const float* __restrict__ x, short* __restrict__ xT)
{
    const int bs = blockIdx.x, bc = blockIdx.y, b = blockIdx.z;
    const int tid = threadIdx.x;
    __shared__ short T[64][72];
    {
        const int cl = tid >> 4;
        const int s4 = (tid & 15) * 4;
        #pragma unroll
        for (int r = 0; r < 4; ++r) {
            const int c = cl + 16 * r;
            float4 v = *(const float4*)&x[((size_t)b * CC + bc * 64 + c) * SB + bs * 64 + s4];
            T[s4 + 0][c] = f2bs(v.x); T[s4 + 1][c] = f2bs(v.y);
            T[s4 + 2][c] = f2bs(v.z); T[s4 + 3][c] = f2bs(v.w);
        }
    }
    __syncthreads();
    {
        const int sl = tid >> 2;
        const int c16 = (tid & 3) * 16;
        short8 v0 = *(const short8*)&T[sl][c16];
        short8 v1 = *(const short8*)&T[sl][c16 + 8];
        short* dst = &xT[((size_t)b * SB + bs * 64 + sl) * CC + bc * 64 + c16];
        *(short8*)&dst[0] = v0;
        *(short8*)&dst[8] = v1;
    }
}

// ---------------------------------------------------------------------------
// vmean[b][c] = (1/S) sum_t v[b][c][t]; also expand mask -> float 0/-FLT_MAX.
// ---------------------------------------------------------------------------
__global__ __launch_bounds__(256)
void vmean_kernel(const short* __restrict__ vN, const int* __restrict__ mask,
                  float* __restrict__ vmean, float* __restrict__ maskf)
{
    const int gi = blockIdx.x * 256 + threadIdx.x;
    if (gi < NB * SB) maskf[gi] = (mask[gi] != 0) ? -FLT_MAX : 0.f;

    const int row = blockIdx.x * 4 + (threadIdx.x >> 6);  // b*CC + c
    const int lane = threadIdx.x & 63;
    const short* p = vN + (size_t)row * SB + lane * 16;
    short8 a = *(const short8*)&p[0];
    short8 b8 = *(const short8*)&p[8];
    float s = 0.f;
    #pragma unroll
    for (int j = 0; j < 8; ++j) s += bs2f(a[j]) + bs2f(b8[j]);
    #pragma unroll
    for (int o = 1; o < 64; o <<= 1) s += __shfl_xor(s, o, 64);
    if (lane == 0) vmean[row] = s * (1.f / 1024.f);
}

// ---------------------------------------------------------------------------
// bf16 MFMA GEMM: Y[b,o,s] = sum_c A[o,c] * X[b,s,c]^T + bias[o]
// 128x128 tile, BK=64, 4 waves (2x2), 4x4 16x16 frags per wave.
// MODE 0 (qkv): o<512 -> qT[b,h,s,d] * (0.125*log2e)  [exp2-domain scores];
//               o<1024 -> kT[b,h,s,d]; else v[b,c,s].
// MODE 1 (proj): fp32 out[b,o,s].
// ---------------------------------------------------------------------------
template<int MODE>
__global__ __launch_bounds__(256)
void gemm_bf16(const short* __restrict__ A, const float* __restrict__ bias,
               const short* __restrict__ BT,
               short* __restrict__ qTo, short* __restrict__ kTo,
               short* __restrict__ vo, float* __restrict__ fo)
{
    const int stile = blockIdx.x * 128;
    const int bo    = blockIdx.y;
    const int b     = blockIdx.z;
    const int tid   = threadIdx.x;
    const int wave = tid >> 6, lane = tid & 63, lg = lane >> 4, ln = lane & 15;
    const int wm = wave >> 1, wn = wave & 1;

    __shared__ short Al[128 * 64];
    __shared__ short Bl[128 * 64];

    f32x4 acc[4][4];
    #pragma unroll
    for (int mt = 0; mt < 4; ++mt)
        #pragma unroll
        for (int nt = 0; nt < 4; ++nt) acc[mt][nt] = (f32x4){0.f, 0.f, 0.f, 0.f};

    const char* Ab = (const char*)(A + (size_t)bo * 128 * 512);
    const char* Bb = (const char*)(BT + ((size_t)b * SB + stile) * 512);

    for (int kc = 0; kc < 512; kc += 64) {
        __syncthreads();
        #pragma unroll
        for (int sw = 0; sw < 4; ++sw) {
            const int lin = tid * 16 + sw * 4096;
            const int row = lin >> 7;
            const int scol = (lin & 127) ^ ((row & 7) << 4);
            gload16(Ab + ((size_t)row * 512 + kc) * 2 + scol,
                    (char*)Al + (wave << 10) + (sw << 12));
            gload16(Bb + ((size_t)row * 512 + kc) * 2 + scol,
                    (char*)Bl + (wave << 10) + (sw << 12));
        }
        __syncthreads();
        #pragma unroll
        for (int kk = 0; kk < 2; ++kk) {
            const int colb = kk * 64 + lg * 16;
            short8 a[4], bb[4];
            #pragma unroll
            for (int mt = 0; mt < 4; ++mt)
                a[mt] = *(const short8*)&Al[sidx(wm * 64 + mt * 16 + ln, colb)];
            #pragma unroll
            for (int nt = 0; nt < 4; ++nt)
                bb[nt] = *(const short8*)&Bl[sidx(wn * 64 + nt * 16 + ln, colb)];
            #pragma unroll
            for (int mt = 0; mt < 4; ++mt)
                #pragma unroll
                for (int nt = 0; nt < 4; ++nt)
                    acc[mt][nt] = __builtin_amdgcn_mfma_f32_16x16x32_bf16(
                        a[mt], bb[nt], acc[mt][nt], 0, 0, 0);
        }
    }

    const int s_base = stile + wn * 64;
    if (MODE == 0) {
        if (bo < 8) {   // q or k -> transposed [b,h,s,d]
            short* dst = (bo < 4) ? qTo : kTo;
            const int h = (bo & 3) * 2 + wm;
            const float sc = (bo < 4) ? 0.18033688011112042f : 1.0f;  // 0.125*log2(e)
            #pragma unroll
            for (int mt = 0; mt < 4; ++mt) {
                const int d0 = mt * 16 + 4 * lg;
                const int o0 = bo * 128 + wm * 64 + d0;
                const float b0 = bias[o0], b1 = bias[o0 + 1],
                            b2 = bias[o0 + 2], b3 = bias[o0 + 3];
                #pragma unroll
                for (int nt = 0; nt < 4; ++nt) {
                    const int s = s_base + nt * 16 + ln;
                    s16x4 pk;
                    pk[0] = f2bs((acc[mt][nt][0] + b0) * sc);
                    pk[1] = f2bs((acc[mt][nt][1] + b1) * sc);
                    pk[2] = f2bs((acc[mt][nt][2] + b2) * sc);
                    pk[3] = f2bs((acc[mt][nt][3] + b3) * sc);
                    *(s16x4*)&dst[(((size_t)b * NH + h) * SB + s) * HD + d0] = pk;
                }
            }
        } else {        // v -> natural [b,c,s]
            #pragma unroll
            for (int mt = 0; mt < 4; ++mt) {
                const int cv0 = (bo - 8) * 128 + wm * 64 + mt * 16 + 4 * lg;
                #pragma unroll
                for (int r = 0; r < 4; ++r) {
                    const float bv = bias[1024 + cv0 + r];
                    #pragma unroll
                    for (int nt = 0; nt < 4; ++nt) {
                        const int s = s_base + nt * 16 + ln;
                        vo[((size_t)b * CC + cv0 + r) * SB + s] = f2bs(acc[mt][nt][r] + bv);
                    }
                }
            }
        }
    } else {            // proj -> fp32 out [b,o,s]
        #pragma unroll
        for (int mt = 0; mt < 4; ++mt) {
            #pragma unroll
            for (int r = 0; r < 4; ++r) {
                const int o = bo * 128 + wm * 64 + mt * 16 + 4 * lg + r;
                const float bv = bias[o];
                #pragma unroll
                for (int nt = 0; nt < 4; ++nt) {
                    const int s = s_base + nt * 16 + ln;
                    fo[((size_t)b * CC + o) * SB + s] = acc[mt][nt][r] + bv;
                }
            }
        }
    }
}

// ---------------------------------------------------------------------------
// Double-buffered MFMA attention + owner-lane (swapped-operand) softmax.
//  - K/V/mask double-buffered in LDS via global_load_lds; tile t+1 staged
//    before compute of tile t; one __syncthreads per tile (R8 structure).
//  - QK^T computed as mfma(K,Q) = S^T: SAME LDS reads / register contents as
//    mfma(Q,K) (operand swap only). Lane ln owns all 16 scores of query ln:
//    softmax reduce = 15 in-reg ops + 2 shfl_xor (vs 4 rows x 8 shuffles).
//  - Ps written as packed b64 (4 bf16/write, <=2-way bank aliasing).
//  - exp2-domain softmax (Q pre-scaled by 0.125*log2e in GEMM epilogue).
//  - Fully-masked rows keep m == -FLT_MAX -> ctx = vmean (reference's
//    uniform softmax over all 1024 keys).
// ---------------------------------------------------------------------------
__global__ __launch_bounds__(256, 4)
void attn_mfma(const short* __restrict__ qT, const short* __restrict__ kT,
               const short* __restrict__ vN, const float* __restrict__ maskf,
               const float* __restrict__ vmean, short* __restrict__ ctxT)
{
    const int L  = blockIdx.x;
    const int qb = 15 - (L >> 6);         // heavy blocks first
    const int bh = L & 63;                // XCD = L%8 = h -> per-(b,h) L2 reuse
    const int b  = bh >> 3, h = bh & 7;
    const int tid = threadIdx.x;
    const int wave = tid >> 6;
    const int lane = tid & 63;
    const int lg = lane >> 4;
    const int ln = lane & 15;

    __shared__ short Ks[2][64 * 64];      // [buf][t][d] swizzled
    __shared__ short Vs[2][64 * 64];      // [buf][d][t] swizzled
    __shared__ float mskL[2][64];         // 0 / -FLT_MAX per key
    __shared__ short Ps[4][16][72];       // per-wave P tile [q][t]

    const char*  kbh = (const char*)(kT + (((size_t)b * NH + h) * SB) * HD);
    const char*  vbh = (const char*)(vN + ((size_t)b * CC + h * HD) * SB);
    const float* mb  = maskf + (size_t)b * SB;

    short8 qa0, qa1;
    {
        const short* qrow = qT + (((size_t)b * NH + h) * SB + qb * 64 + wave * 16 + ln) * HD;
        qa0 = *(const short8*)&qrow[8 * lg];
        qa1 = *(const short8*)&qrow[32 + 8 * lg];
    }

    float m_ = -FLT_MAX, l_ = 0.f;        // per-lane: state of query ln
    f32x4 acc[4];
    #pragma unroll
    for (int nt = 0; nt < 4; ++nt) acc[nt] = (f32x4){0.f, 0.f, 0.f, 0.f};

    // ---- staging helper (2 x 8KB via global_load_lds + 64 mask floats) ----
    auto stage = [&](int tb, int bi) {
        #pragma unroll
        for (int sw = 0; sw < 2; ++sw) {
            const int lin = tid * 16 + sw * 4096;
            const int row = lin >> 7;
            const int scol = (lin & 127) ^ ((row & 7) << 4);
            gload16(kbh + (size_t)tb * 128 + row * 128 + scol,
                    (char*)&Ks[bi][0] + (wave << 10) + (sw << 12));
            gload16(vbh + (size_t)row * (SB * 2) + tb * 2 + scol,
                    (char*)&Vs[bi][0] + (wave << 10) + (sw << 12));
        }
        if (tid < 64) mskL[bi][tid] = mb[tb + tid];
    };

    int cur = 0;
    stage(0, 0);
    __syncthreads();

    for (int t = 0; t <= qb; ++t) {
        // ---- issue next tile's staging BEFORE compute (overlap) ----
        if (t < qb) stage((t + 1) * 64, cur ^ 1);

        // ---- swapped QK^T: sc[nt][r] = S[q=ln][key 16nt+4lg+r] ----
        f32x4 sc[4];
        #pragma unroll
        for (int nt = 0; nt < 4; ++nt) {
            short8 kb0 = *(const short8*)&Ks[cur][sidx(ln + 16 * nt, lg * 16)];
            short8 kb1 = *(const short8*)&Ks[cur][sidx(ln + 16 * nt, 64 + lg * 16)];
            f32x4 z = (f32x4){0.f, 0.f, 0.f, 0.f};
            z = __builtin_amdgcn_mfma_f32_16x16x32_bf16(kb0, qa0, z, 0, 0, 0);
            z = __builtin_amdgcn_mfma_f32_16x16x32_bf16(kb1, qa1, z, 0, 0, 0);
            sc[nt] = z;
        }

        // ---- padding mask (float4 add from LDS; key = 16nt+4lg+r) ----
        #pragma unroll
        for (int nt = 0; nt < 4; ++nt) {
            const float4 mf = *(const float4*)&mskL[cur][16 * nt + 4 * lg];
            sc[nt][0] += mf.x; sc[nt][1] += mf.y;
            sc[nt][2] += mf.z; sc[nt][3] += mf.w;
        }
        // ---- causal on diagonal tile (tile-local: key > query) ----
        if (t == qb) {
            const int so = wave * 16 + ln;
            #pragma unroll
            for (int nt = 0; nt < 4; ++nt)
                #pragma unroll
                for (int r = 0; r < 4; ++r)
                    if (16 * nt + 4 * lg + r > so) sc[nt][r] = -FLT_MAX;
        }

        // ---- owner-lane online softmax (exp2 domain) ----
        float mx = sc[0][0];
        #pragma unroll
        for (int nt = 0; nt < 4; ++nt)
            #pragma unroll
            for (int r = 0; r < 4; ++r)
                if (nt | r) mx = fmaxf(mx, sc[nt][r]);
        mx = fmaxf(mx, __shfl_xor(mx, 16, 64));
        mx = fmaxf(mx, __shfl_xor(mx, 32, 64));
        const float mnew = fmaxf(m_, mx);
        const float fq = exp2f(m_ - mnew);    // 0-0 -> 1 (all-masked rows)
        float rs = 0.f;
        #pragma unroll
        for (int nt = 0; nt < 4; ++nt) {
            s16x4 pk;
            #pragma unroll
            for (int r = 0; r < 4; ++r) {
                const float p = exp2f(sc[nt][r] - mnew);
                rs += p;
                pk[r] = f2bs(p);
            }
            *(s16x4*)&Ps[wave][ln][16 * nt + 4 * lg] = pk;   // packed b64 write
        }
        rs += __shfl_xor(rs, 16, 64);
        rs += __shfl_xor(rs, 32, 64);
        l_ = l_ * fq + rs;
        m_ = mnew;

        // ---- rescale acc (acc rows = queries 4lg+r; fetch their f) ----
        {
            float fr[4];
            #pragma unroll
            for (int r = 0; r < 4; ++r) fr[r] = __shfl(fq, 4 * lg + r, 64);
            #pragma unroll
            for (int nt = 0; nt < 4; ++nt)
                #pragma unroll
                for (int r = 0; r < 4; ++r) acc[nt][r] *= fr[r];
        }

        // ---- PV from LDS buf[cur] (Ps roundtrip within-wave) ----
        const short8 pa0 = *(const short8*)&Ps[wave][ln][8 * lg];
        const short8 pa1 = *(const short8*)&Ps[wave][ln][32 + 8 * lg];
        #pragma unroll
        for (int nt = 0; nt < 4; ++nt) {
            short8 vb0 = *(const short8*)&Vs[cur][sidx(16 * nt + ln, lg * 16)];
            short8 vb1 = *(const short8*)&Vs[cur][sidx(16 * nt + ln, 64 + lg * 16)];
            acc[nt] = __builtin_amdgcn_mfma_f32_16x16x32_bf16(pa0, vb0, acc[nt], 0, 0, 0);
            acc[nt] = __builtin_amdgcn_mfma_f32_16x16x32_bf16(pa1, vb1, acc[nt], 0, 0, 0);
        }

        // ---- publish buf[cur^1] (drains prefetch after compute) ----
        if (t < qb) {
            __syncthreads();
            cur ^= 1;
        }
    }

    // ---- epilogue: per-query l/m via shfl, normalize or vmean, store ----
    float rl[4], mch[4];
    #pragma unroll
    for (int r = 0; r < 4; ++r) {
        rl[r]  = 1.f / __shfl(l_, 4 * lg + r, 64);
        mch[r] = __shfl(m_, 4 * lg + r, 64);
    }
    const float* vmb = vmean + (size_t)b * CC + h * HD;
    #pragma unroll
    for (int nt = 0; nt < 4; ++nt) {
        const int c = h * HD + 16 * nt + ln;
        const float vmv = vmb[16 * nt + ln];
        #pragma unroll
        for (int r = 0; r < 4; ++r) {
            const int s = qb * 64 + wave * 16 + 4 * lg + r;
            const float val = (mch[r] == -FLT_MAX) ? vmv : acc[nt][r] * rl[r];
            ctxT[((size_t)b * SB + s) * CC + c] = f2bs(val);
        }
    }
}

extern "C" void kernel_launch(void* const* d_in, const int* in_sizes, int n_in,
                              void* d_out, int out_size, void* d_ws, size_t ws_size,
                              hipStream_t stream) {
    const float* x      = (const float*)d_in[0];
    const int*   amask  = (const int*)d_in[1];
    const float* qkv_w  = (const float*)d_in[2];
    const float* qkv_b  = (const float*)d_in[3];
    const float* proj_w = (const float*)d_in[4];
    const float* proj_b = (const float*)d_in[5];
    float* out = (float*)d_out;

    short* xT    = (short*)d_ws;                       // (B,S,C)
    short* w1b   = xT  + (size_t)NB * SB * CC;         // (1536,512)
    short* w2b   = w1b + (size_t)1536 * 512;           // (512,512)
    short* qT    = w2b + (size_t)512 * 512;            // (B,H,S,D)
    short* kT    = qT  + (size_t)NB * NH * SB * HD;    // (B,H,S,D)
    short* vN    = kT  + (size_t)NB * NH * SB * HD;    // (B,C,S)
    short* ctxT  = vN  + (size_t)NB * CC * SB;         // (B,S,C)
    float* vmean = (float*)(ctxT + (size_t)NB * SB * CC);  // (B,C)
    float* maskf = vmean + (size_t)NB * CC;            // (B,S)

    cvt_weights<<<1024, 256, 0, stream>>>(qkv_w, proj_w, w1b, w2b);
    transpose_x<<<dim3(SB / 64, CC / 64, NB), 256, 0, stream>>>(x, xT);
    gemm_bf16<0><<<dim3(8, 12, NB), 256, 0, stream>>>(
        w1b, qkv_b, xT, qT, kT, vN, nullptr);
    vmean_kernel<<<NB * CC / 4, 256, 0, stream>>>(vN, amask, vmean, maskf);
    attn_mfma<<<dim3(1024, 1, 1), 256, 0, stream>>>(qT, kT, vN, maskf, vmean, ctxT);
    gemm_bf16<1><<<dim3(8, 4, NB), 256, 0, stream>>>(
        w2b, proj_b, ctxT, nullptr, nullptr, nullptr, out);
}

// Round 10
// 85.141 us; speedup vs baseline: 1.8807x; 1.0168x over previous
//
#include <hip/hip_runtime.h>
#include <cfloat>
#include <math.h>

#define SB 1024   // sequence length S = H*W
#define CC 512    // channels
#define NB 8      // batch
#define NH 8      // heads
#define HD 64     // head dim

typedef short short8 __attribute__((ext_vector_type(8)));
typedef short s16x4 __attribute__((ext_vector_type(4)));
typedef float f32x4 __attribute__((ext_vector_type(4)));

__device__ __forceinline__ short f2bs(float f) {
    union { float f; unsigned u; } x; x.f = f;
    unsigned r = x.u + 0x7fffu + ((x.u >> 16) & 1u);   // RNE to bf16
    return (short)(r >> 16);
}

__device__ __forceinline__ float bs2f(short s) {
    union { unsigned u; float f; } x;
    x.u = ((unsigned)(unsigned short)s) << 16;
    return x.f;
}

__device__ __forceinline__ void gload16(const void* g, void* l) {
    __builtin_amdgcn_global_load_lds(
        (const __attribute__((address_space(1))) unsigned int*)g,
        (__attribute__((address_space(3))) unsigned int*)l, 16, 0, 0);
}

// swizzled short-index within a [rows][64-short] LDS tile (128B rows)
__device__ __forceinline__ int sidx(int row, int colb) {
    return row * 64 + ((colb ^ ((row & 7) << 4)) >> 1);
}

// ---------------------------------------------------------------------------
// Convert both weight matrices fp32 -> bf16 (natural [o][c] layout).
// ---------------------------------------------------------------------------
__global__ __launch_bounds__(256)
void cvt_weights(const float* __restrict__ w1, const float* __restrict__ w2,
                 short* __restrict__ o1, short* __restrict__ o2)
{
    const int i4 = blockIdx.x * 256 + threadIdx.x;
    const int N1 = 1536 * 512 / 4;
    if (i4 < N1) {
        float4 v = *(const float4*)&w1[(size_t)i4 * 4];
        s16x4 p; p[0] = f2bs(v.x); p[1] = f2bs(v.y); p[2] = f2bs(v.z); p[3] = f2bs(v.w);
        *(s16x4*)&o1[(size_t)i4 * 4] = p;
    } else {
        const int j = i4 - N1;
        float4 v = *(const float4*)&w2[(size_t)j * 4];
        s16x4 p; p[0] = f2bs(v.x); p[1] = f2bs(v.y); p[2] = f2bs(v.z); p[3] = f2bs(v.w);
        *(s16x4*)&o2[(size_t)j * 4] = p;
    }
}

// ---------------------------------------------------------------------------
// x (B, C, S) fp32  ->  xT (B, S, C) bf16   (64x64 LDS tile transpose)
// ---------------------------------------------------------------------------
__global__ __launch_bounds__(256)
void transpose_x(const float* __restrict__ x, short* __restrict__ xT)
{
    const int bs = blockIdx.x, bc = blockIdx.y, b = blockIdx.z;
    const int tid = threadIdx.x;
    __shared__ short T[64][72];
    {
        const int cl = tid >> 4;
        const int s4 = (tid & 15) * 4;
        #pragma unroll
        for (int r = 0; r < 4; ++r) {
            const int c = cl + 16 * r;
            float4 v = *(const float4*)&x[((size_t)b * CC + bc * 64 + c) * SB + bs * 64 + s4];
            T[s4 + 0][c] = f2bs(v.x); T[s4 + 1][c] = f2bs(v.y);
            T[s4 + 2][c] = f2bs(v.z); T[s4 + 3][c] = f2bs(v.w);
        }
    }
    __syncthreads();
    {
        const int sl = tid >> 2;
        const int c16 = (tid & 3) * 16;
        short8 v0 = *(const short8*)&T[sl][c16];
        short8 v1 = *(const short8*)&T[sl][c16 + 8];
        short* dst = &xT[((size_t)b * SB + bs * 64 + sl) * CC + bc * 64 + c16];
        *(short8*)&dst[0] = v0;
        *(short8*)&dst[8] = v1;
    }
}

// ---------------------------------------------------------------------------
// vmean[b][c] = (1/S) sum_t v[b][c][t]; also expand mask -> float 0/-FLT_MAX.
// ---------------------------------------------------------------------------
__global__ __launch_bounds__(256)
void vmean_kernel(const short* __restrict__ vN, const int* __restrict__ mask,
                  float* __restrict__ vmean, float* __restrict__ maskf)
{
    const int gi = blockIdx.x * 256 + threadIdx.x;
    if (gi < NB * SB) maskf[gi] = (mask[gi] != 0) ? -FLT_MAX : 0.f;

    const int row = blockIdx.x * 4 + (threadIdx.x >> 6);  // b*CC + c
    const int lane = threadIdx.x & 63;
    const short* p = vN + (size_t)row * SB + lane * 16;
    short8 a = *(const short8*)&p[0];
    short8 b8 = *(const short8*)&p[8];
    float s = 0.f;
    #pragma unroll
    for (int j = 0; j < 8; ++j) s += bs2f(a[j]) + bs2f(b8[j]);
    #pragma unroll
    for (int o = 1; o < 64; o <<= 1) s += __shfl_xor(s, o, 64);
    if (lane == 0) vmean[row] = s * (1.f / 1024.f);
}

// ---------------------------------------------------------------------------
// bf16 MFMA GEMM: Y[b,o,s] = sum_c A[o,c] * X[b,s,c]^T + bias[o]
// 128x128 tile, BK=64, 4 waves (2x2), 4x4 16x16 frags per wave.
// MODE 0 (qkv): o<512 -> qT[b,h,s,d] * (0.125*log2e)  [exp2-domain scores];
//               o<1024 -> kT[b,h,s,d]; else v[b,c,s].
// MODE 1 (proj): fp32 out[b,o,s].
// ---------------------------------------------------------------------------
template<int MODE>
__global__ __launch_bounds__(256)
void gemm_bf16(const short* __restrict__ A, const float* __restrict__ bias,
               const short* __restrict__ BT,
               short* __restrict__ qTo, short* __restrict__ kTo,
               short* __restrict__ vo, float* __restrict__ fo)
{
    const int stile = blockIdx.x * 128;
    const int bo    = blockIdx.y;
    const int b     = blockIdx.z;
    const int tid   = threadIdx.x;
    const int wave = tid >> 6, lane = tid & 63, lg = lane >> 4, ln = lane & 15;
    const int wm = wave >> 1, wn = wave & 1;

    __shared__ short Al[128 * 64];
    __shared__ short Bl[128 * 64];

    f32x4 acc[4][4];
    #pragma unroll
    for (int mt = 0; mt < 4; ++mt)
        #pragma unroll
        for (int nt = 0; nt < 4; ++nt) acc[mt][nt] = (f32x4){0.f, 0.f, 0.f, 0.f};

    const char* Ab = (const char*)(A + (size_t)bo * 128 * 512);
    const char* Bb = (const char*)(BT + ((size_t)b * SB + stile) * 512);

    for (int kc = 0; kc < 512; kc += 64) {
        __syncthreads();
        #pragma unroll
        for (int sw = 0; sw < 4; ++sw) {
            const int lin = tid * 16 + sw * 4096;
            const int row = lin >> 7;
            const int scol = (lin & 127) ^ ((row & 7) << 4);
            gload16(Ab + ((size_t)row * 512 + kc) * 2 + scol,
                    (char*)Al + (wave << 10) + (sw << 12));
            gload16(Bb + ((size_t)row * 512 + kc) * 2 + scol,
                    (char*)Bl + (wave << 10) + (sw << 12));
        }
        __syncthreads();
        #pragma unroll
        for (int kk = 0; kk < 2; ++kk) {
            const int colb = kk * 64 + lg * 16;
            short8 a[4], bb[4];
            #pragma unroll
            for (int mt = 0; mt < 4; ++mt)
                a[mt] = *(const short8*)&Al[sidx(wm * 64 + mt * 16 + ln, colb)];
            #pragma unroll
            for (int nt = 0; nt < 4; ++nt)
                bb[nt] = *(const short8*)&Bl[sidx(wn * 64 + nt * 16 + ln, colb)];
            #pragma unroll
            for (int mt = 0; mt < 4; ++mt)
                #pragma unroll
                for (int nt = 0; nt < 4; ++nt)
                    acc[mt][nt] = __builtin_amdgcn_mfma_f32_16x16x32_bf16(
                        a[mt], bb[nt], acc[mt][nt], 0, 0, 0);
        }
    }

    const int s_base = stile + wn * 64;
    if (MODE == 0) {
        if (bo < 8) {   // q or k -> transposed [b,h,s,d]
            short* dst = (bo < 4) ? qTo : kTo;
            const int h = (bo & 3) * 2 + wm;
            const float sc = (bo < 4) ? 0.18033688011112042f : 1.0f;  // 0.125*log2(e)
            #pragma unroll
            for (int mt = 0; mt < 4; ++mt) {
                const int d0 = mt * 16 + 4 * lg;
                const int o0 = bo * 128 + wm * 64 + d0;
                const float b0 = bias[o0], b1 = bias[o0 + 1],
                            b2 = bias[o0 + 2], b3 = bias[o0 + 3];
                #pragma unroll
                for (int nt = 0; nt < 4; ++nt) {
                    const int s = s_base + nt * 16 + ln;
                    s16x4 pk;
                    pk[0] = f2bs((acc[mt][nt][0] + b0) * sc);
                    pk[1] = f2bs((acc[mt][nt][1] + b1) * sc);
                    pk[2] = f2bs((acc[mt][nt][2] + b2) * sc);
                    pk[3] = f2bs((acc[mt][nt][3] + b3) * sc);
                    *(s16x4*)&dst[(((size_t)b * NH + h) * SB + s) * HD + d0] = pk;
                }
            }
        } else {        // v -> natural [b,c,s]
            #pragma unroll
            for (int mt = 0; mt < 4; ++mt) {
                const int cv0 = (bo - 8) * 128 + wm * 64 + mt * 16 + 4 * lg;
                #pragma unroll
                for (int r = 0; r < 4; ++r) {
                    const float bv = bias[1024 + cv0 + r];
                    #pragma unroll
                    for (int nt = 0; nt < 4; ++nt) {
                        const int s = s_base + nt * 16 + ln;
                        vo[((size_t)b * CC + cv0 + r) * SB + s] = f2bs(acc[mt][nt][r] + bv);
                    }
                }
            }
        }
    } else {            // proj -> fp32 out [b,o,s]
        #pragma unroll
        for (int mt = 0; mt < 4; ++mt) {
            #pragma unroll
            for (int r = 0; r < 4; ++r) {
                const int o = bo * 128 + wm * 64 + mt * 16 + 4 * lg + r;
                const float bv = bias[o];
                #pragma unroll
                for (int nt = 0; nt < 4; ++nt) {
                    const int s = s_base + nt * 16 + ln;
                    fo[((size_t)b * CC + o) * SB + s] = acc[mt][nt][r] + bv;
                }
            }
        }
    }
}

// ---------------------------------------------------------------------------
// Double-buffered MFMA attention, fully owner-lane softmax AND accumulator.
//  - QK^T as mfma(K,Q) = S^T: lane ln owns all 16 scores of query ln.
//  - PV as mfma(V,P): SAME LDS reads as mfma(P,V) (A<->B swap only), but
//    output cols = queries -> acc[nt][r] = ctx[q=ln][d=16nt+4lg+r].
//    Rescale/normalize use own-lane fq/l_/m_: ZERO broadcast shuffles.
//  - Per tile cross-lane ops: just 2+2 shfl_xor reduces (max, sum).
//  - Defer-max (T13): skip {fq, acc rescale} when __all(pmax <= m_+11.5)
//    (11.5 = 8*log2e, exp2 domain; P <= 2^11.5 safe in bf16/f32; all-masked
//    edge cases wash out via fq=0 or the vmean override).
//  - K/V/mask double-buffered via global_load_lds, tile t+1 staged before
//    compute of tile t, one __syncthreads per tile (R8 pipeline).
//  - Fully-masked rows keep m == -FLT_MAX -> ctx = vmean (reference's
//    uniform softmax over all 1024 keys).
// ---------------------------------------------------------------------------
__global__ __launch_bounds__(256, 4)
void attn_mfma(const short* __restrict__ qT, const short* __restrict__ kT,
               const short* __restrict__ vN, const float* __restrict__ maskf,
               const float* __restrict__ vmean, short* __restrict__ ctxT)
{
    const int L  = blockIdx.x;
    const int qb = 15 - (L >> 6);         // heavy blocks first
    const int bh = L & 63;                // XCD = L%8 = h -> per-(b,h) L2 reuse
    const int b  = bh >> 3, h = bh & 7;
    const int tid = threadIdx.x;
    const int wave = tid >> 6;
    const int lane = tid & 63;
    const int lg = lane >> 4;
    const int ln = lane & 15;

    __shared__ short Ks[2][64 * 64];      // [buf][t][d] swizzled
    __shared__ short Vs[2][64 * 64];      // [buf][d][t] swizzled
    __shared__ float mskL[2][64];         // 0 / -FLT_MAX per key
    __shared__ short Ps[4][16][72];       // per-wave P tile [q][t]

    const char*  kbh = (const char*)(kT + (((size_t)b * NH + h) * SB) * HD);
    const char*  vbh = (const char*)(vN + ((size_t)b * CC + h * HD) * SB);
    const float* mb  = maskf + (size_t)b * SB;

    short8 qa0, qa1;
    {
        const short* qrow = qT + (((size_t)b * NH + h) * SB + qb * 64 + wave * 16 + ln) * HD;
        qa0 = *(const short8*)&qrow[8 * lg];
        qa1 = *(const short8*)&qrow[32 + 8 * lg];
    }

    float m_ = -FLT_MAX, l_ = 0.f;        // per-lane: state of query ln
    f32x4 acc[4];                         // acc[nt][r] = ctx[q=ln][d=16nt+4lg+r]
    #pragma unroll
    for (int nt = 0; nt < 4; ++nt) acc[nt] = (f32x4){0.f, 0.f, 0.f, 0.f};

    // ---- staging helper (2 x 8KB via global_load_lds + 64 mask floats) ----
    auto stage = [&](int tb, int bi) {
        #pragma unroll
        for (int sw = 0; sw < 2; ++sw) {
            const int lin = tid * 16 + sw * 4096;
            const int row = lin >> 7;
            const int scol = (lin & 127) ^ ((row & 7) << 4);
            gload16(kbh + (size_t)tb * 128 + row * 128 + scol,
                    (char*)&Ks[bi][0] + (wave << 10) + (sw << 12));
            gload16(vbh + (size_t)row * (SB * 2) + tb * 2 + scol,
                    (char*)&Vs[bi][0] + (wave << 10) + (sw << 12));
        }
        if (tid < 64) mskL[bi][tid] = mb[tb + tid];
    };

    int cur = 0;
    stage(0, 0);
    __syncthreads();

    for (int t = 0; t <= qb; ++t) {
        // ---- issue next tile's staging BEFORE compute (overlap) ----
        if (t < qb) stage((t + 1) * 64, cur ^ 1);

        // ---- swapped QK^T: sc[nt][r] = S[q=ln][key 16nt+4lg+r] ----
        f32x4 sc[4];
        #pragma unroll
        for (int nt = 0; nt < 4; ++nt) {
            short8 kb0 = *(const short8*)&Ks[cur][sidx(ln + 16 * nt, lg * 16)];
            short8 kb1 = *(const short8*)&Ks[cur][sidx(ln + 16 * nt, 64 + lg * 16)];
            f32x4 z = (f32x4){0.f, 0.f, 0.f, 0.f};
            z = __builtin_amdgcn_mfma_f32_16x16x32_bf16(kb0, qa0, z, 0, 0, 0);
            z = __builtin_amdgcn_mfma_f32_16x16x32_bf16(kb1, qa1, z, 0, 0, 0);
            sc[nt] = z;
        }

        // ---- padding mask (float4 add from LDS; key = 16nt+4lg+r) ----
        #pragma unroll
        for (int nt = 0; nt < 4; ++nt) {
            const float4 mf = *(const float4*)&mskL[cur][16 * nt + 4 * lg];
            sc[nt][0] += mf.x; sc[nt][1] += mf.y;
            sc[nt][2] += mf.z; sc[nt][3] += mf.w;
        }
        // ---- causal on diagonal tile (tile-local: key > query) ----
        if (t == qb) {
            const int so = wave * 16 + ln;
            #pragma unroll
            for (int nt = 0; nt < 4; ++nt)
                #pragma unroll
                for (int r = 0; r < 4; ++r)
                    if (16 * nt + 4 * lg + r > so) sc[nt][r] = -FLT_MAX;
        }

        // ---- owner-lane max reduce (15 in-reg + 2 shfl) ----
        float mx = sc[0][0];
        #pragma unroll
        for (int nt = 0; nt < 4; ++nt)
            #pragma unroll
            for (int r = 0; r < 4; ++r)
                if (nt | r) mx = fmaxf(mx, sc[nt][r]);
        mx = fmaxf(mx, __shfl_xor(mx, 16, 64));
        mx = fmaxf(mx, __shfl_xor(mx, 32, 64));

        // ---- defer-max: only rescale when some query's max really grew ----
        if (!__all(mx <= m_ + 11.5f)) {
            const float mnew = fmaxf(m_, mx);
            const float fq = exp2f(m_ - mnew);   // 0-0 -> 1 (all-masked rows)
            l_ *= fq;
            #pragma unroll
            for (int nt = 0; nt < 4; ++nt)
                #pragma unroll
                for (int r = 0; r < 4; ++r) acc[nt][r] *= fq;
            m_ = mnew;
        }

        // ---- P = exp2(sc - m_), row-sum, packed Ps write ----
        float rs = 0.f;
        #pragma unroll
        for (int nt = 0; nt < 4; ++nt) {
            s16x4 pk;
            #pragma unroll
            for (int r = 0; r < 4; ++r) {
                const float p = exp2f(sc[nt][r] - m_);
                rs += p;
                pk[r] = f2bs(p);
            }
            *(s16x4*)&Ps[wave][ln][16 * nt + 4 * lg] = pk;   // packed b64 write
        }
        rs += __shfl_xor(rs, 16, 64);
        rs += __shfl_xor(rs, 32, 64);
        l_ += rs;

        // ---- PV as mfma(V, P): output cols = queries (own lane) ----
        const short8 pa0 = *(const short8*)&Ps[wave][ln][8 * lg];
        const short8 pa1 = *(const short8*)&Ps[wave][ln][32 + 8 * lg];
        #pragma unroll
        for (int nt = 0; nt < 4; ++nt) {
            short8 va0 = *(const short8*)&Vs[cur][sidx(16 * nt + ln, lg * 16)];
            short8 va1 = *(const short8*)&Vs[cur][sidx(16 * nt + ln, 64 + lg * 16)];
            acc[nt] = __builtin_amdgcn_mfma_f32_16x16x32_bf16(va0, pa0, acc[nt], 0, 0, 0);
            acc[nt] = __builtin_amdgcn_mfma_f32_16x16x32_bf16(va1, pa1, acc[nt], 0, 0, 0);
        }

        // ---- publish buf[cur^1] (drains prefetch after compute) ----
        if (t < qb) {
            __syncthreads();
            cur ^= 1;
        }
    }

    // ---- epilogue: own-lane normalize (or vmean), packed s16x4 stores ----
    const float rl = 1.f / l_;
    const bool dead = (m_ == -FLT_MAX);
    const float* vmb = vmean + (size_t)b * CC + h * HD;
    const int s = qb * 64 + wave * 16 + ln;
    short* crow = ctxT + ((size_t)b * SB + s) * CC + h * HD;
    #pragma unroll
    for (int nt = 0; nt < 4; ++nt) {
        const int d0 = 16 * nt + 4 * lg;
        const float4 vm4 = *(const float4*)&vmb[d0];
        s16x4 pk;
        pk[0] = f2bs(dead ? vm4.x : acc[nt][0] * rl);
        pk[1] = f2bs(dead ? vm4.y : acc[nt][1] * rl);
        pk[2] = f2bs(dead ? vm4.z : acc[nt][2] * rl);
        pk[3] = f2bs(dead ? vm4.w : acc[nt][3] * rl);
        *(s16x4*)&crow[d0] = pk;
    }
}

extern "C" void kernel_launch(void* const* d_in, const int* in_sizes, int n_in,
                              void* d_out, int out_size, void* d_ws, size_t ws_size,
                              hipStream_t stream) {
    const float* x      = (const float*)d_in[0];
    const int*   amask  = (const int*)d_in[1];
    const float* qkv_w  = (const float*)d_in[2];
    const float* qkv_b  = (const float*)d_in[3];
    const float* proj_w = (const float*)d_in[4];
    const float* proj_b = (const float*)d_in[5];
    float* out = (float*)d_out;

    short* xT    = (short*)d_ws;                       // (B,S,C)
    short* w1b   = xT  + (size_t)NB * SB * CC;         // (1536,512)
    short* w2b   = w1b + (size_t)1536 * 512;           // (512,512)
    short* qT    = w2b + (size_t)512 * 512;            // (B,H,S,D)
    short* kT    = qT  + (size_t)NB * NH * SB * HD;    // (B,H,S,D)
    short* vN    = kT  + (size_t)NB * NH * SB * HD;    // (B,C,S)
    short* ctxT  = vN  + (size_t)NB * CC * SB;         // (B,S,C)
    float* vmean = (float*)(ctxT + (size_t)NB * SB * CC);  // (B,C)
    float* maskf = vmean + (size_t)NB * CC;            // (B,S)

    cvt_weights<<<1024, 256, 0, stream>>>(qkv_w, proj_w, w1b, w2b);
    transpose_x<<<dim3(SB / 64, CC / 64, NB), 256, 0, stream>>>(x, xT);
    gemm_bf16<0><<<dim3(8, 12, NB), 256, 0, stream>>>(
        w1b, qkv_b, xT, qT, kT, vN, nullptr);
    vmean_kernel<<<NB * CC / 4, 256, 0, stream>>>(vN, amask, vmean, maskf);
    attn_mfma<<<dim3(1024, 1, 1), 256, 0, stream>>>(qT, kT, vN, maskf, vmean, ctxT);
    gemm_bf16<1><<<dim3(8, 4, NB), 256, 0, stream>>>(
        w2b, proj_b, ctxT, nullptr, nullptr, nullptr, out);
}